// Round 2
// baseline (3042.468 us; speedup 1.0000x reference)
//
#include <hip/hip_runtime.h>

#define VOCAB   32000
#define WORDVEC 256
#define HIDDEN  512
#define TSTEPS  256
#define NBATCH  16
#define NROWS   (TSTEPS*NBATCH)   // 4096
#define GATES   (4*HIDDEN)        // 2048
#define NVB     125               // 32000/256
#define NWG     64                // LSTM workgroups

typedef __attribute__((ext_vector_type(8))) short short8;
typedef __attribute__((ext_vector_type(4))) float f32x4;

__device__ __forceinline__ unsigned short f2bf(float x){
    union { float f; unsigned int u; } v; v.f = x;
    unsigned int r = v.u + 0x7fffu + ((v.u >> 16) & 1u);
    return (unsigned short)(r >> 16);
}

// ---------------------------------------------------------------- K0a:
// W_vocab (fp32 [512][32000]) -> WvT (bf16 [32000][512]) via LDS transpose
__global__ void wv_transpose(const float* __restrict__ Wv, unsigned short* __restrict__ WvT){
    __shared__ float s[64][65];
    int v0 = blockIdx.x * 64;
    int k0 = blockIdx.y * 64;
    int tid = threadIdx.x;
    for (int i = 0; i < 16; ++i){
        int lin = tid + i*256;
        int kk = lin >> 6, vv = lin & 63;
        s[kk][vv] = Wv[(long)(k0+kk)*VOCAB + v0 + vv];
    }
    __syncthreads();
    for (int i = 0; i < 16; ++i){
        int lin = tid + i*256;
        int vv = lin >> 6, kk = lin & 63;
        WvT[(long)(v0+vv)*HIDDEN + k0 + kk] = f2bf(s[kk][vv]);
    }
}

// ---------------------------------------------------------------- K0b:
// Wh (fp32 [512][2048]) -> Whp: per-WG MFMA-B-fragment-ordered bf16 image.
// WG w owns hidden units j0=w*8..+8; permuted col p in [0,32): gate g=p>>3, jl=p&7.
// Fragment f = kt*2+nt (kt<16, nt<2); lane L holds B[k=kt*32+(L>>4)*8+jj][n=nt*16+(L&15)].
__global__ void whp_prep(const float* __restrict__ Wh, unsigned short* __restrict__ Whp){
    int w = blockIdx.x; int tid = threadIdx.x;
    for (int item = tid; item < 2048; item += 256){
        int f = item >> 6;          // 0..31
        int L = item & 63;
        int kt = f >> 1, nt = f & 1;
        int q = L >> 4, ln = L & 15;
        int p = nt*16 + ln, g = p >> 3, jl = p & 7;
        int col = g*HIDDEN + w*8 + jl;
        short8 vvec;
        for (int jj = 0; jj < 8; ++jj){
            int k = kt*32 + q*8 + jj;
            vvec[jj] = (short)f2bf(Wh[(long)k*GATES + col]);
        }
        *(short8*)(Whp + ((long)w*2048 + item)*8) = vvec;
    }
}

// ---------------------------------------------------------------- K0c:
// broadcast h_init into hglob buffer 0 (bf16, [16][512])
__global__ void hg_init(const float* __restrict__ h_init, unsigned short* __restrict__ hg){
    int idx = blockIdx.x*256 + threadIdx.x;   // 8192
    int j = idx & 511;
    hg[idx] = f2bf(h_init[j]);
}

// ---------------------------------------------------------------- K1:
// xw[r=t*16+n][k] = b[k] + sum_d W_embed[cap_in[n][t]][d] * Wx[d][k]   (fp32)
__global__ __launch_bounds__(256) void embed_xw(const int* __restrict__ captions,
        const float* __restrict__ Wemb, const float* __restrict__ Wx,
        const float* __restrict__ b, float* __restrict__ xw){
    __shared__ float xs[8][WORDVEC];
    __shared__ int toks[8];
    int tid = threadIdx.x;
    int r0 = blockIdx.x * 8;
    if (tid < 8){
        int r = r0 + tid; int t = r >> 4, n = r & 15;
        toks[tid] = captions[n*257 + t];
    }
    __syncthreads();
    for (int i = 0; i < 8; ++i){
        int lin = tid + i*256;
        int ri = lin >> 8, d = lin & 255;
        xs[ri][d] = Wemb[(long)toks[ri]*WORDVEC + d];
    }
    __syncthreads();
    float4 b0 = *(const float4*)(b + tid*4);
    float4 b1 = *(const float4*)(b + 1024 + tid*4);
    float acc[8][8];
    for (int ri = 0; ri < 8; ++ri){
        acc[ri][0]=b0.x; acc[ri][1]=b0.y; acc[ri][2]=b0.z; acc[ri][3]=b0.w;
        acc[ri][4]=b1.x; acc[ri][5]=b1.y; acc[ri][6]=b1.z; acc[ri][7]=b1.w;
    }
    for (int d = 0; d < WORDVEC; ++d){
        float4 w0 = *(const float4*)(Wx + (long)d*GATES + tid*4);
        float4 w1 = *(const float4*)(Wx + (long)d*GATES + 1024 + tid*4);
        #pragma unroll
        for (int ri = 0; ri < 8; ++ri){
            float xv = xs[ri][d];
            acc[ri][0] += xv*w0.x; acc[ri][1] += xv*w0.y;
            acc[ri][2] += xv*w0.z; acc[ri][3] += xv*w0.w;
            acc[ri][4] += xv*w1.x; acc[ri][5] += xv*w1.y;
            acc[ri][6] += xv*w1.z; acc[ri][7] += xv*w1.w;
        }
    }
    for (int ri = 0; ri < 8; ++ri){
        float4 o0 = {acc[ri][0],acc[ri][1],acc[ri][2],acc[ri][3]};
        float4 o1 = {acc[ri][4],acc[ri][5],acc[ri][6],acc[ri][7]};
        *(float4*)(xw + (long)(r0+ri)*GATES + tid*4) = o0;
        *(float4*)(xw + (long)(r0+ri)*GATES + 1024 + tid*4) = o1;
    }
}

// ---------------------------------------------------------------- K2:
// Batched LSTM: 64 WGs x 128 threads, persistent. Wh slice (32KB bf16) LDS-resident.
// Per step: a-slice = h @ Wh_slice via mfma 16x16x32 bf16 (M=16 seqs, N=32 cols),
// gates fp32, c in registers, h double-buffered in global, counter barrier/step.
__global__ __launch_bounds__(128) void lstm_mfma(const float* __restrict__ xw,
        const unsigned short* __restrict__ Whp, unsigned short* __restrict__ hg,
        unsigned short* __restrict__ hs, int* __restrict__ bar){
    __shared__ unsigned short whs[32*64*8];   // 32 KB
    __shared__ float a_s[16][32];
    int w = blockIdx.x;          // 0..63
    int tid = threadIdx.x;       // 0..127
    int wv = tid >> 6;           // nt
    int L = tid & 63;
    int q = L >> 4, ln = L & 15;
    { // stage Wh slice
        const int4* src = (const int4*)(Whp + (long)w*2048*8);
        int4* dst = (int4*)whs;
        for (int i = tid; i < 2048; i += 128) dst[i] = src[i];
    }
    int s_idx = tid >> 3, jl = tid & 7;   // (sequence, local hidden)
    float c_r = 0.f;
    __syncthreads();
    for (int t = 0; t < TSTEPS; ++t){
        // prefetch xw for gate phase (independent of h)
        long xb = (long)(t*16 + s_idx)*GATES + w*8 + jl;
        float xg0 = xw[xb], xg1 = xw[xb+512], xg2 = xw[xb+1024], xg3 = xw[xb+1536];

        const unsigned short* hr = hg + (t & 1)*8192;
        unsigned short*       hw = hg + ((t+1) & 1)*8192;

        f32x4 acc = {0.f,0.f,0.f,0.f};
        #pragma unroll
        for (int kt = 0; kt < 16; ++kt){
            short8 a  = *(const short8*)(hr + ln*HIDDEN + kt*32 + q*8);
            short8 bf = *(const short8*)(whs + ((kt*2 + wv)*64 + L)*8);
            acc = __builtin_amdgcn_mfma_f32_16x16x32_bf16(a, bf, acc, 0, 0, 0);
        }
        // D layout: row(seq) = q*4+reg, col(p) = wv*16+ln
        #pragma unroll
        for (int r = 0; r < 4; ++r) a_s[q*4 + r][wv*16 + ln] = acc[r];
        __syncthreads();
        // gate phase: thread -> (s_idx, jl)
        float ai = a_s[s_idx][jl]      + xg0;
        float af = a_s[s_idx][8  + jl] + xg1;
        float ao = a_s[s_idx][16 + jl] + xg2;
        float ag = a_s[s_idx][24 + jl] + xg3;
        float ig = 1.f/(1.f + __expf(-ai));
        float fg = 1.f/(1.f + __expf(-af));
        float og = 1.f/(1.f + __expf(-ao));
        float gg = tanhf(ag);
        c_r = fg*c_r + ig*gg;
        float hv = og * tanhf(c_r);
        unsigned short hb = f2bf(hv);
        hw[s_idx*HIDDEN + w*8 + jl] = hb;
        hs[((long)s_idx*TSTEPS + t)*HIDDEN + w*8 + jl] = hb;
        // grid barrier (monotone counter, device scope)
        __threadfence();
        __syncthreads();
        if (tid == 0){
            atomicAdd(bar, 1);
            while (__hip_atomic_load(bar, __ATOMIC_ACQUIRE, __HIP_MEMORY_SCOPE_AGENT)
                   < NWG*(t+1)) { }
        }
        __syncthreads();
        __threadfence();   // acquire: invalidate L1 before reading others' h
    }
}

// ---------------------------------------------------------------- K3:
// Fused vocab GEMM + per-row softmax partials. BM=64, BN=256, 256 thr (4 waves).
// A = hs bf16 [4096][512], B = WvT bf16 [32000][512] (B^T layout, m91-verified).
__global__ __launch_bounds__(256) void vocab_gemm(const unsigned short* __restrict__ hs,
        const unsigned short* __restrict__ WvT, const float* __restrict__ bvoc,
        const int* __restrict__ captions, float* __restrict__ pmax,
        float* __restrict__ psum, float* __restrict__ tlog){
    int bn = blockIdx.x;    // 0..124
    int bm = blockIdx.y;    // 0..63
    int tid = threadIdx.x;
    int wv = tid >> 6, L = tid & 63;
    int q = L >> 4, ln = L & 15;
    __shared__ int   tgt_s[64];
    __shared__ float wmax_s[4][64], wsum_s[4][64];
    if (tid < 64){
        int rg = bm*64 + tid;
        tgt_s[tid] = captions[(rg >> 8)*257 + (rg & 255) + 1];
    }
    __syncthreads();
    f32x4 acc[4][4];
    for (int mt=0;mt<4;++mt) for (int nt=0;nt<4;++nt) acc[mt][nt] = (f32x4){0.f,0.f,0.f,0.f};
    int colb = bn*256 + wv*64;
    for (int kt = 0; kt < 16; ++kt){
        short8 a[4], bb[4];
        #pragma unroll
        for (int mt=0;mt<4;++mt){
            int row = bm*64 + mt*16 + ln;
            a[mt] = *(const short8*)(hs + (long)row*HIDDEN + kt*32 + q*8);
        }
        #pragma unroll
        for (int nt=0;nt<4;++nt){
            int v = colb + nt*16 + ln;
            bb[nt] = *(const short8*)(WvT + (long)v*HIDDEN + kt*32 + q*8);
        }
        #pragma unroll
        for (int mt=0;mt<4;++mt)
            #pragma unroll
            for (int nt=0;nt<4;++nt)
                acc[mt][nt] = __builtin_amdgcn_mfma_f32_16x16x32_bf16(a[mt], bb[nt], acc[mt][nt], 0,0,0);
    }
    float bv[4];
    #pragma unroll
    for (int nt=0;nt<4;++nt) bv[nt] = bvoc[colb + nt*16 + ln];
    #pragma unroll
    for (int mt=0;mt<4;++mt) for (int nt=0;nt<4;++nt) for (int r=0;r<4;++r)
        acc[mt][nt][r] += bv[nt];
    // target-logit grab (exactly one lane grid-wide matches per row)
    #pragma unroll
    for (int mt=0;mt<4;++mt) for (int r=0;r<4;++r){
        int rl = mt*16 + q*4 + r;
        int tg = tgt_s[rl] - colb;
        if (tg >= 0 && tg < 64){
            int nt = tg >> 4;
            if ((tg & 15) == ln) tlog[bm*64 + rl] = acc[mt][nt][r];
        }
    }
    // per-row max & sumexp over this block's 256 cols
    #pragma unroll
    for (int mt=0;mt<4;++mt){
        #pragma unroll
        for (int r=0;r<4;++r){
            float m = fmaxf(fmaxf(acc[mt][0][r],acc[mt][1][r]), fmaxf(acc[mt][2][r],acc[mt][3][r]));
            for (int d=1; d<16; d<<=1) m = fmaxf(m, __shfl_xor(m, d, 16));
            float s = __expf(acc[mt][0][r]-m) + __expf(acc[mt][1][r]-m)
                    + __expf(acc[mt][2][r]-m) + __expf(acc[mt][3][r]-m);
            for (int d=1; d<16; d<<=1) s += __shfl_xor(s, d, 16);
            if (ln == 0){ int rl = mt*16 + q*4 + r; wmax_s[wv][rl] = m; wsum_s[wv][rl] = s; }
        }
    }
    __syncthreads();
    if (tid < 64){
        float M = fmaxf(fmaxf(wmax_s[0][tid],wmax_s[1][tid]), fmaxf(wmax_s[2][tid],wmax_s[3][tid]));
        float S = 0.f;
        for (int ww=0; ww<4; ++ww) S += wsum_s[ww][tid]*__expf(wmax_s[ww][tid]-M);
        pmax[(long)bn*NROWS + bm*64 + tid] = M;
        psum[(long)bn*NROWS + bm*64 + tid] = S;
    }
}

// ---------------------------------------------------------------- K4:
// combine 125 partials per row -> lse -> masked NLL -> loss/N
__global__ __launch_bounds__(256) void reduce_loss(const float* __restrict__ pmax,
        const float* __restrict__ psum, const float* __restrict__ tlog,
        const int* __restrict__ captions, float* __restrict__ out){
    int r = blockIdx.x*256 + threadIdx.x;
    float M = -1e30f;
    for (int p=0;p<NVB;++p) M = fmaxf(M, pmax[(long)p*NROWS + r]);
    float S = 0.f;
    for (int p=0;p<NVB;++p) S += psum[(long)p*NROWS + r]*__expf(pmax[(long)p*NROWS + r]-M);
    float lse = M + logf(S);
    float nll = lse - tlog[r];
    int tok = captions[(r >> 8)*257 + (r & 255) + 1];
    float val = (tok != 0) ? nll : 0.f;
    __shared__ float red[256];
    red[threadIdx.x] = val; __syncthreads();
    for (int s=128; s>0; s>>=1){
        if (threadIdx.x < s) red[threadIdx.x] += red[threadIdx.x+s];
        __syncthreads();
    }
    if (threadIdx.x == 0) atomicAdd(out, red[0] * (1.0f/16.0f));
}

// ---------------------------------------------------------------- launch
extern "C" void kernel_launch(void* const* d_in, const int* in_sizes, int n_in,
                              void* d_out, int out_size, void* d_ws, size_t ws_size,
                              hipStream_t stream){
    const int*   captions = (const int*)  d_in[0];
    const float* Wemb     = (const float*)d_in[1];
    const float* Wx       = (const float*)d_in[2];
    const float* Wh       = (const float*)d_in[3];
    const float* b        = (const float*)d_in[4];
    const float* Wv       = (const float*)d_in[5];
    const float* bvoc     = (const float*)d_in[6];
    const float* h_init   = (const float*)d_in[7];

    char* ws = (char*)d_ws;
    float*          xw   = (float*)         (ws + 0);          // 33554432 B
    unsigned short* WvT  = (unsigned short*)(ws + 33554432);   // 32768000 B
    unsigned short* hs   = (unsigned short*)(ws + 66322432);   //  4194304 B
    float*          pmax = (float*)         (ws + 70516736);   //  2048000 B
    float*          psum = (float*)         (ws + 72564736);   //  2048000 B
    float*          tlog = (float*)         (ws + 74612736);   //    16384 B
    unsigned short* Whp  = (unsigned short*)(ws + 74629120);   //  2097152 B
    unsigned short* hg   = (unsigned short*)(ws + 76726272);   //    32768 B (2 bufs)
    int*            bar  = (int*)           (ws + 76759040);   //      128 B

    float* out_f = (float*)d_out;

    (void)hipMemsetAsync(d_out, 0, sizeof(float), stream);
    (void)hipMemsetAsync(bar, 0, 128, stream);

    hipLaunchKernelGGL(wv_transpose, dim3(500, 8), dim3(256), 0, stream, Wv, WvT);
    hipLaunchKernelGGL(whp_prep,     dim3(64),     dim3(256), 0, stream, Wh, Whp);
    hipLaunchKernelGGL(hg_init,      dim3(32),     dim3(256), 0, stream, h_init, hg);
    hipLaunchKernelGGL(embed_xw,     dim3(512),    dim3(256), 0, stream, captions, Wemb, Wx, b, xw);
    hipLaunchKernelGGL(lstm_mfma,    dim3(NWG),    dim3(128), 0, stream, xw, Whp, hg, hs, bar);
    hipLaunchKernelGGL(vocab_gemm,   dim3(NVB,64), dim3(256), 0, stream, hs, WvT, bvoc, captions, pmax, psum, tlog);
    hipLaunchKernelGGL(reduce_loss,  dim3(16),     dim3(256), 0, stream, pmax, psum, tlog, captions, out_f);
}

// Round 3
// 2822.424 us; speedup vs baseline: 1.0780x; 1.0780x over previous
//
#include <hip/hip_runtime.h>

#define VOCAB   32000
#define WORDVEC 256
#define HIDDEN  512
#define TSTEPS  256
#define NBATCH  16
#define NROWS   (TSTEPS*NBATCH)   // 4096
#define GATES   (4*HIDDEN)        // 2048
#define NVB     125               // 32000/256
#define NWG     32                // LSTM workgroups (32 x 16 hidden units)

typedef __attribute__((ext_vector_type(8))) short short8;
typedef __attribute__((ext_vector_type(4))) float f32x4;

__device__ __forceinline__ unsigned short f2bf(float x){
    union { float f; unsigned int u; } v; v.f = x;
    unsigned int r = v.u + 0x7fffu + ((v.u >> 16) & 1u);
    return (unsigned short)(r >> 16);
}

// ---------------------------------------------------------------- K0a:
// W_vocab (fp32 [512][32000]) -> WvT (bf16 [32000][512]) via LDS transpose
__global__ void wv_transpose(const float* __restrict__ Wv, unsigned short* __restrict__ WvT){
    __shared__ float s[64][65];
    int v0 = blockIdx.x * 64;
    int k0 = blockIdx.y * 64;
    int tid = threadIdx.x;
    for (int i = 0; i < 16; ++i){
        int lin = tid + i*256;
        int kk = lin >> 6, vv = lin & 63;
        s[kk][vv] = Wv[(long)(k0+kk)*VOCAB + v0 + vv];
    }
    __syncthreads();
    for (int i = 0; i < 16; ++i){
        int lin = tid + i*256;
        int vv = lin >> 6, kk = lin & 63;
        WvT[(long)(v0+vv)*HIDDEN + k0 + kk] = f2bf(s[kk][vv]);
    }
}

// ---------------------------------------------------------------- K0b:
// Wh (fp32 [512][2048]) -> Whp: per-WG MFMA-B-fragment-ordered bf16 image.
// WG w owns hidden units w*16..+16. N-tile nt == gate g (cols p = nt*16+ln).
// Fragment f = kt*4+nt (kt<16); lane L holds B[k=kt*32+(L>>4)*8+jj][n=nt*16+(L&15)].
__global__ void whp_prep(const float* __restrict__ Wh, unsigned short* __restrict__ Whp){
    int w = blockIdx.x; int tid = threadIdx.x;   // 32 blocks x 256 thr
    for (int item = tid; item < 4096; item += 256){
        int f = item >> 6;          // 0..63
        int L = item & 63;
        int kt = f >> 2, nt = f & 3;
        int q = L >> 4, ln = L & 15;
        int col = nt*HIDDEN + w*16 + ln;   // gate nt, unit w*16+ln
        short8 vvec;
        for (int jj = 0; jj < 8; ++jj){
            int k = kt*32 + q*8 + jj;
            vvec[jj] = (short)f2bf(Wh[(long)k*GATES + col]);
        }
        *(short8*)(Whp + ((long)w*4096 + item)*8) = vvec;
    }
}

// ---------------------------------------------------------------- K0c:
// broadcast h_init into hglob buffer 0 (bf16, [16][512])
__global__ void hg_init(const float* __restrict__ h_init, unsigned short* __restrict__ hg){
    int idx = blockIdx.x*256 + threadIdx.x;   // 8192
    int j = idx & 511;
    hg[idx] = f2bf(h_init[j]);
}

// ---------------------------------------------------------------- K1:
// xw[r=t*16+n][k] = b[k] + sum_d W_embed[cap_in[n][t]][d] * Wx[d][k]   (fp32)
__global__ __launch_bounds__(256) void embed_xw(const int* __restrict__ captions,
        const float* __restrict__ Wemb, const float* __restrict__ Wx,
        const float* __restrict__ b, float* __restrict__ xw){
    __shared__ float xs[8][WORDVEC];
    __shared__ int toks[8];
    int tid = threadIdx.x;
    int r0 = blockIdx.x * 8;
    if (tid < 8){
        int r = r0 + tid; int t = r >> 4, n = r & 15;
        toks[tid] = captions[n*257 + t];
    }
    __syncthreads();
    for (int i = 0; i < 8; ++i){
        int lin = tid + i*256;
        int ri = lin >> 8, d = lin & 255;
        xs[ri][d] = Wemb[(long)toks[ri]*WORDVEC + d];
    }
    __syncthreads();
    float4 b0 = *(const float4*)(b + tid*4);
    float4 b1 = *(const float4*)(b + 1024 + tid*4);
    float acc[8][8];
    for (int ri = 0; ri < 8; ++ri){
        acc[ri][0]=b0.x; acc[ri][1]=b0.y; acc[ri][2]=b0.z; acc[ri][3]=b0.w;
        acc[ri][4]=b1.x; acc[ri][5]=b1.y; acc[ri][6]=b1.z; acc[ri][7]=b1.w;
    }
    for (int d = 0; d < WORDVEC; ++d){
        float4 w0 = *(const float4*)(Wx + (long)d*GATES + tid*4);
        float4 w1 = *(const float4*)(Wx + (long)d*GATES + 1024 + tid*4);
        #pragma unroll
        for (int ri = 0; ri < 8; ++ri){
            float xv = xs[ri][d];
            acc[ri][0] += xv*w0.x; acc[ri][1] += xv*w0.y;
            acc[ri][2] += xv*w0.z; acc[ri][3] += xv*w0.w;
            acc[ri][4] += xv*w1.x; acc[ri][5] += xv*w1.y;
            acc[ri][6] += xv*w1.z; acc[ri][7] += xv*w1.w;
        }
    }
    for (int ri = 0; ri < 8; ++ri){
        float4 o0 = {acc[ri][0],acc[ri][1],acc[ri][2],acc[ri][3]};
        float4 o1 = {acc[ri][4],acc[ri][5],acc[ri][6],acc[ri][7]};
        *(float4*)(xw + (long)(r0+ri)*GATES + tid*4) = o0;
        *(float4*)(xw + (long)(r0+ri)*GATES + 1024 + tid*4) = o1;
    }
}

// ---------------------------------------------------------------- K2:
// Batched LSTM: 32 WGs x 256 threads, persistent. Wh slice (64KB bf16) LDS-resident.
// Per step: a-slice = h @ Wh_slice, 4 waves = 4 gates, M=16 seqs, N=16 units each.
// Grid barrier: counter atomicAdd + last-arriver sets flag on a SEPARATE line;
// others poll flag read-only with s_sleep backoff (kills the RMW hot-line).
__global__ __launch_bounds__(256) void lstm_mfma(const float* __restrict__ xw,
        const unsigned short* __restrict__ Whp, unsigned short* __restrict__ hg,
        unsigned short* __restrict__ hs, int* __restrict__ bar){
    __shared__ unsigned short whs[64*64*8];   // 64 KB
    __shared__ float a_s[4][16][16];          // 4 KB
    int w = blockIdx.x;          // 0..31
    int tid = threadIdx.x;       // 0..255
    int wv = tid >> 6;           // wave = gate = N-tile (0..3)
    int L = tid & 63;
    int q = L >> 4, ln = L & 15;
    { // stage Wh slice
        const int4* src = (const int4*)(Whp + (long)w*4096*8);
        int4* dst = (int4*)whs;
        for (int i = tid; i < 4096; i += 256) dst[i] = src[i];
    }
    int s_idx = tid >> 4, jl = tid & 15;   // (sequence, local hidden unit)
    float c_r = 0.f;
    int* flag = bar + 32;                  // byte offset 128: separate cacheline
    __syncthreads();
    for (int t = 0; t < TSTEPS; ++t){
        // xw for gate phase (constant input, independent of barrier)
        long xb = (long)(t*16 + s_idx)*GATES + w*16 + jl;
        float xg0 = xw[xb], xg1 = xw[xb+512], xg2 = xw[xb+1024], xg3 = xw[xb+1536];

        const unsigned short* hr = hg + (t & 1)*8192;
        unsigned short*       hw = hg + ((t+1) & 1)*8192;

        f32x4 acc = {0.f,0.f,0.f,0.f};
        #pragma unroll
        for (int kt = 0; kt < 16; ++kt){
            short8 a  = *(const short8*)(hr + ln*HIDDEN + kt*32 + q*8);
            short8 bf = *(const short8*)(whs + ((kt*4 + wv)*64 + L)*8);
            acc = __builtin_amdgcn_mfma_f32_16x16x32_bf16(a, bf, acc, 0, 0, 0);
        }
        // D layout: row(seq) = q*4+reg, col(unit) = ln; wave wv = gate
        #pragma unroll
        for (int r = 0; r < 4; ++r) a_s[wv][q*4 + r][ln] = acc[r];
        __syncthreads();
        // gate phase: thread -> (s_idx, jl)
        float ai = a_s[0][s_idx][jl] + xg0;
        float af = a_s[1][s_idx][jl] + xg1;
        float ao = a_s[2][s_idx][jl] + xg2;
        float ag = a_s[3][s_idx][jl] + xg3;
        float ig = 1.f/(1.f + __expf(-ai));
        float fg = 1.f/(1.f + __expf(-af));
        float og = 1.f/(1.f + __expf(-ao));
        float gg = tanhf(ag);
        c_r = fg*c_r + ig*gg;
        float hv = og * tanhf(c_r);
        unsigned short hb = f2bf(hv);
        hw[s_idx*HIDDEN + w*16 + jl] = hb;    // critical-path h exchange
        // ---- grid barrier (sense flag) ----
        __threadfence();    // release: drain + make h writes agent-visible
        __syncthreads();
        if (tid == 0){
            unsigned old = atomicAdd((unsigned*)bar, 1u);
            if (old == (unsigned)(NWG*(t+1)) - 1u){
                __hip_atomic_store(flag, t+1, __ATOMIC_RELEASE, __HIP_MEMORY_SCOPE_AGENT);
            } else {
                while (__hip_atomic_load(flag, __ATOMIC_ACQUIRE, __HIP_MEMORY_SCOPE_AGENT) < t+1)
                    __builtin_amdgcn_s_sleep(1);
            }
        }
        __syncthreads();
        __threadfence();    // acquire: invalidate L1/L2 before reading others' h
        // hs store off the critical path: drains during next step's MFMA phase
        hs[((long)s_idx*TSTEPS + t)*HIDDEN + w*16 + jl] = hb;
    }
}

// ---------------------------------------------------------------- K3:
// Fused vocab GEMM + per-row softmax partials. BM=64, BN=256, 256 thr (4 waves).
// A = hs bf16 [4096][512], B = WvT bf16 [32000][512] (B^T layout, m91-verified).
__global__ __launch_bounds__(256) void vocab_gemm(const unsigned short* __restrict__ hs,
        const unsigned short* __restrict__ WvT, const float* __restrict__ bvoc,
        const int* __restrict__ captions, float* __restrict__ pmax,
        float* __restrict__ psum, float* __restrict__ tlog){
    int bn = blockIdx.x;    // 0..124
    int bm = blockIdx.y;    // 0..63
    int tid = threadIdx.x;
    int wv = tid >> 6, L = tid & 63;
    int q = L >> 4, ln = L & 15;
    __shared__ int   tgt_s[64];
    __shared__ float wmax_s[4][64], wsum_s[4][64];
    if (tid < 64){
        int rg = bm*64 + tid;
        tgt_s[tid] = captions[(rg >> 8)*257 + (rg & 255) + 1];
    }
    __syncthreads();
    f32x4 acc[4][4];
    for (int mt=0;mt<4;++mt) for (int nt=0;nt<4;++nt) acc[mt][nt] = (f32x4){0.f,0.f,0.f,0.f};
    int colb = bn*256 + wv*64;
    for (int kt = 0; kt < 16; ++kt){
        short8 a[4], bb[4];
        #pragma unroll
        for (int mt=0;mt<4;++mt){
            int row = bm*64 + mt*16 + ln;
            a[mt] = *(const short8*)(hs + (long)row*HIDDEN + kt*32 + q*8);
        }
        #pragma unroll
        for (int nt=0;nt<4;++nt){
            int v = colb + nt*16 + ln;
            bb[nt] = *(const short8*)(WvT + (long)v*HIDDEN + kt*32 + q*8);
        }
        #pragma unroll
        for (int mt=0;mt<4;++mt)
            #pragma unroll
            for (int nt=0;nt<4;++nt)
                acc[mt][nt] = __builtin_amdgcn_mfma_f32_16x16x32_bf16(a[mt], bb[nt], acc[mt][nt], 0,0,0);
    }
    float bv[4];
    #pragma unroll
    for (int nt=0;nt<4;++nt) bv[nt] = bvoc[colb + nt*16 + ln];
    #pragma unroll
    for (int mt=0;mt<4;++mt) for (int nt=0;nt<4;++nt) for (int r=0;r<4;++r)
        acc[mt][nt][r] += bv[nt];
    // target-logit grab (exactly one lane grid-wide matches per row)
    #pragma unroll
    for (int mt=0;mt<4;++mt) for (int r=0;r<4;++r){
        int rl = mt*16 + q*4 + r;
        int tg = tgt_s[rl] - colb;
        if (tg >= 0 && tg < 64){
            int nt = tg >> 4;
            if ((tg & 15) == ln) tlog[bm*64 + rl] = acc[mt][nt][r];
        }
    }
    // per-row max & sumexp over this block's 256 cols
    #pragma unroll
    for (int mt=0;mt<4;++mt){
        #pragma unroll
        for (int r=0;r<4;++r){
            float m = fmaxf(fmaxf(acc[mt][0][r],acc[mt][1][r]), fmaxf(acc[mt][2][r],acc[mt][3][r]));
            for (int d=1; d<16; d<<=1) m = fmaxf(m, __shfl_xor(m, d, 16));
            float s = __expf(acc[mt][0][r]-m) + __expf(acc[mt][1][r]-m)
                    + __expf(acc[mt][2][r]-m) + __expf(acc[mt][3][r]-m);
            for (int d=1; d<16; d<<=1) s += __shfl_xor(s, d, 16);
            if (ln == 0){ int rl = mt*16 + q*4 + r; wmax_s[wv][rl] = m; wsum_s[wv][rl] = s; }
        }
    }
    __syncthreads();
    if (tid < 64){
        float M = fmaxf(fmaxf(wmax_s[0][tid],wmax_s[1][tid]), fmaxf(wmax_s[2][tid],wmax_s[3][tid]));
        float S = 0.f;
        for (int ww=0; ww<4; ++ww) S += wsum_s[ww][tid]*__expf(wmax_s[ww][tid]-M);
        pmax[(long)bn*NROWS + bm*64 + tid] = M;
        psum[(long)bn*NROWS + bm*64 + tid] = S;
    }
}

// ---------------------------------------------------------------- K4:
// combine 125 partials per row -> lse -> masked NLL -> loss/N
__global__ __launch_bounds__(256) void reduce_loss(const float* __restrict__ pmax,
        const float* __restrict__ psum, const float* __restrict__ tlog,
        const int* __restrict__ captions, float* __restrict__ out){
    int r = blockIdx.x*256 + threadIdx.x;
    float M = -1e30f;
    for (int p=0;p<NVB;++p) M = fmaxf(M, pmax[(long)p*NROWS + r]);
    float S = 0.f;
    for (int p=0;p<NVB;++p) S += psum[(long)p*NROWS + r]*__expf(pmax[(long)p*NROWS + r]-M);
    float lse = M + logf(S);
    float nll = lse - tlog[r];
    int tok = captions[(r >> 8)*257 + (r & 255) + 1];
    float val = (tok != 0) ? nll : 0.f;
    __shared__ float red[256];
    red[threadIdx.x] = val; __syncthreads();
    for (int s=128; s>0; s>>=1){
        if (threadIdx.x < s) red[threadIdx.x] += red[threadIdx.x+s];
        __syncthreads();
    }
    if (threadIdx.x == 0) atomicAdd(out, red[0] * (1.0f/16.0f));
}

// ---------------------------------------------------------------- launch
extern "C" void kernel_launch(void* const* d_in, const int* in_sizes, int n_in,
                              void* d_out, int out_size, void* d_ws, size_t ws_size,
                              hipStream_t stream){
    const int*   captions = (const int*)  d_in[0];
    const float* Wemb     = (const float*)d_in[1];
    const float* Wx       = (const float*)d_in[2];
    const float* Wh       = (const float*)d_in[3];
    const float* b        = (const float*)d_in[4];
    const float* Wv       = (const float*)d_in[5];
    const float* bvoc     = (const float*)d_in[6];
    const float* h_init   = (const float*)d_in[7];

    char* ws = (char*)d_ws;
    float*          xw   = (float*)         (ws + 0);          // 33554432 B
    unsigned short* WvT  = (unsigned short*)(ws + 33554432);   // 32768000 B
    unsigned short* hs   = (unsigned short*)(ws + 66322432);   //  4194304 B
    float*          pmax = (float*)         (ws + 70516736);   //  2048000 B
    float*          psum = (float*)         (ws + 72564736);   //  2048000 B
    float*          tlog = (float*)         (ws + 74612736);   //    16384 B
    unsigned short* Whp  = (unsigned short*)(ws + 74629120);   //  2097152 B
    unsigned short* hg   = (unsigned short*)(ws + 76726272);   //    32768 B (2 bufs)
    int*            bar  = (int*)           (ws + 76759040);   //      256 B (counter + flag line)

    float* out_f = (float*)d_out;

    (void)hipMemsetAsync(d_out, 0, sizeof(float), stream);
    (void)hipMemsetAsync(bar, 0, 256, stream);

    hipLaunchKernelGGL(wv_transpose, dim3(500, 8), dim3(256), 0, stream, Wv, WvT);
    hipLaunchKernelGGL(whp_prep,     dim3(NWG),    dim3(256), 0, stream, Wh, Whp);
    hipLaunchKernelGGL(hg_init,      dim3(32),     dim3(256), 0, stream, h_init, hg);
    hipLaunchKernelGGL(embed_xw,     dim3(512),    dim3(256), 0, stream, captions, Wemb, Wx, b, xw);
    hipLaunchKernelGGL(lstm_mfma,    dim3(NWG),    dim3(256), 0, stream, xw, Whp, hg, hs, bar);
    hipLaunchKernelGGL(vocab_gemm,   dim3(NVB,64), dim3(256), 0, stream, hs, WvT, bvoc, captions, pmax, psum, tlog);
    hipLaunchKernelGGL(reduce_loss,  dim3(16),     dim3(256), 0, stream, pmax, psum, tlog, captions, out_f);
}

// Round 4
// 2762.192 us; speedup vs baseline: 1.1015x; 1.0218x over previous
//
#include <hip/hip_runtime.h>

#define VOCAB   32000
#define WORDVEC 256
#define HIDDEN  512
#define TSTEPS  256
#define NBATCH  16
#define NROWS   (TSTEPS*NBATCH)   // 4096
#define GATES   (4*HIDDEN)        // 2048
#define NVB     125               // 32000/256
#define NWG     32                // LSTM workgroups (32 x 16 hidden units)

typedef __attribute__((ext_vector_type(8))) short short8;
typedef __attribute__((ext_vector_type(4))) float f32x4;

__device__ __forceinline__ unsigned short f2bf(float x){
    union { float f; unsigned int u; } v; v.f = x;
    unsigned int r = v.u + 0x7fffu + ((v.u >> 16) & 1u);
    return (unsigned short)(r >> 16);
}

// ---------------------------------------------------------------- K0a:
// W_vocab (fp32 [512][32000]) -> WvT (bf16 [32000][512]) via LDS transpose
__global__ void wv_transpose(const float* __restrict__ Wv, unsigned short* __restrict__ WvT){
    __shared__ float s[64][65];
    int v0 = blockIdx.x * 64;
    int k0 = blockIdx.y * 64;
    int tid = threadIdx.x;
    for (int i = 0; i < 16; ++i){
        int lin = tid + i*256;
        int kk = lin >> 6, vv = lin & 63;
        s[kk][vv] = Wv[(long)(k0+kk)*VOCAB + v0 + vv];
    }
    __syncthreads();
    for (int i = 0; i < 16; ++i){
        int lin = tid + i*256;
        int vv = lin >> 6, kk = lin & 63;
        WvT[(long)(v0+vv)*HIDDEN + k0 + kk] = f2bf(s[kk][vv]);
    }
}

// ---------------------------------------------------------------- K0b:
// Wh (fp32 [512][2048]) -> Whp: per-WG MFMA-B-fragment-ordered bf16 image.
// WG w owns hidden units w*16..+16. N-tile nt == gate g (cols p = nt*16+ln).
// Fragment f = kt*4+nt (kt<16); lane L holds B[k=kt*32+(L>>4)*8+jj][n=nt*16+(L&15)].
__global__ void whp_prep(const float* __restrict__ Wh, unsigned short* __restrict__ Whp){
    int w = blockIdx.x; int tid = threadIdx.x;   // 32 blocks x 256 thr
    for (int item = tid; item < 4096; item += 256){
        int f = item >> 6;          // 0..63
        int L = item & 63;
        int kt = f >> 2, nt = f & 3;
        int q = L >> 4, ln = L & 15;
        int col = nt*HIDDEN + w*16 + ln;   // gate nt, unit w*16+ln
        short8 vvec;
        for (int jj = 0; jj < 8; ++jj){
            int k = kt*32 + q*8 + jj;
            vvec[jj] = (short)f2bf(Wh[(long)k*GATES + col]);
        }
        *(short8*)(Whp + ((long)w*4096 + item)*8) = vvec;
    }
}

// ---------------------------------------------------------------- K0c:
// broadcast h_init into hglob buffer 0 (bf16, [16][512])
__global__ void hg_init(const float* __restrict__ h_init, unsigned short* __restrict__ hg){
    int idx = blockIdx.x*256 + threadIdx.x;   // 8192
    int j = idx & 511;
    hg[idx] = f2bf(h_init[j]);
}

// ---------------------------------------------------------------- K1:
// xw[r=t*16+n][k] = b[k] + sum_d W_embed[cap_in[n][t]][d] * Wx[d][k]   (fp32)
__global__ __launch_bounds__(256) void embed_xw(const int* __restrict__ captions,
        const float* __restrict__ Wemb, const float* __restrict__ Wx,
        const float* __restrict__ b, float* __restrict__ xw){
    __shared__ float xs[8][WORDVEC];
    __shared__ int toks[8];
    int tid = threadIdx.x;
    int r0 = blockIdx.x * 8;
    if (tid < 8){
        int r = r0 + tid; int t = r >> 4, n = r & 15;
        toks[tid] = captions[n*257 + t];
    }
    __syncthreads();
    for (int i = 0; i < 8; ++i){
        int lin = tid + i*256;
        int ri = lin >> 8, d = lin & 255;
        xs[ri][d] = Wemb[(long)toks[ri]*WORDVEC + d];
    }
    __syncthreads();
    float4 b0 = *(const float4*)(b + tid*4);
    float4 b1 = *(const float4*)(b + 1024 + tid*4);
    float acc[8][8];
    for (int ri = 0; ri < 8; ++ri){
        acc[ri][0]=b0.x; acc[ri][1]=b0.y; acc[ri][2]=b0.z; acc[ri][3]=b0.w;
        acc[ri][4]=b1.x; acc[ri][5]=b1.y; acc[ri][6]=b1.z; acc[ri][7]=b1.w;
    }
    for (int d = 0; d < WORDVEC; ++d){
        float4 w0 = *(const float4*)(Wx + (long)d*GATES + tid*4);
        float4 w1 = *(const float4*)(Wx + (long)d*GATES + 1024 + tid*4);
        #pragma unroll
        for (int ri = 0; ri < 8; ++ri){
            float xv = xs[ri][d];
            acc[ri][0] += xv*w0.x; acc[ri][1] += xv*w0.y;
            acc[ri][2] += xv*w0.z; acc[ri][3] += xv*w0.w;
            acc[ri][4] += xv*w1.x; acc[ri][5] += xv*w1.y;
            acc[ri][6] += xv*w1.z; acc[ri][7] += xv*w1.w;
        }
    }
    for (int ri = 0; ri < 8; ++ri){
        float4 o0 = {acc[ri][0],acc[ri][1],acc[ri][2],acc[ri][3]};
        float4 o1 = {acc[ri][4],acc[ri][5],acc[ri][6],acc[ri][7]};
        *(float4*)(xw + (long)(r0+ri)*GATES + tid*4) = o0;
        *(float4*)(xw + (long)(r0+ri)*GATES + 1024 + tid*4) = o1;
    }
}

// ---------------------------------------------------------------- K2:
// Batched LSTM: 32 WGs x 256 threads, persistent. Wh slice (64KB bf16) LDS-resident.
// Per step: a-slice = h @ Wh_slice, 4 waves = 4 gates, M=16 seqs, N=16 units each.
// Barrier: RELAXED flag poll (no per-poll buffer_inv!) + exactly one acquire
// fence per step. Release fence before counter add makes h LLC-visible first.
__global__ __launch_bounds__(256) void lstm_mfma(const float* __restrict__ xw,
        const unsigned short* __restrict__ Whp, unsigned short* __restrict__ hg,
        unsigned short* __restrict__ hs, int* __restrict__ bar){
    __shared__ unsigned short whs[64*64*8];   // 64 KB
    __shared__ float a_s[4][16][16];          // 4 KB
    int w = blockIdx.x;          // 0..31
    int tid = threadIdx.x;       // 0..255
    int wv = tid >> 6;           // wave = gate = N-tile (0..3)
    int L = tid & 63;
    int q = L >> 4, ln = L & 15;
    { // stage Wh slice
        const int4* src = (const int4*)(Whp + (long)w*4096*8);
        int4* dst = (int4*)whs;
        for (int i = tid; i < 4096; i += 256) dst[i] = src[i];
    }
    int s_idx = tid >> 4, jl = tid & 15;   // (sequence, local hidden unit)
    float c_r = 0.f;
    int* flag = bar + 32;                  // byte offset 128: separate cacheline
    __syncthreads();
    for (int t = 0; t < TSTEPS; ++t){
        // xw for gate phase (constant input, independent of barrier)
        long xb = (long)(t*16 + s_idx)*GATES + w*16 + jl;
        float xg0 = xw[xb], xg1 = xw[xb+512], xg2 = xw[xb+1024], xg3 = xw[xb+1536];

        const unsigned short* hr = hg + (t & 1)*8192;
        unsigned short*       hw = hg + ((t+1) & 1)*8192;

        f32x4 acc = {0.f,0.f,0.f,0.f};
        #pragma unroll
        for (int kt = 0; kt < 16; ++kt){
            short8 a  = *(const short8*)(hr + ln*HIDDEN + kt*32 + q*8);
            short8 bf = *(const short8*)(whs + ((kt*4 + wv)*64 + L)*8);
            acc = __builtin_amdgcn_mfma_f32_16x16x32_bf16(a, bf, acc, 0, 0, 0);
        }
        // D layout: row(seq) = q*4+reg, col(unit) = ln; wave wv = gate
        #pragma unroll
        for (int r = 0; r < 4; ++r) a_s[wv][q*4 + r][ln] = acc[r];
        __syncthreads();
        // gate phase: thread -> (s_idx, jl)
        float ai = a_s[0][s_idx][jl] + xg0;
        float af = a_s[1][s_idx][jl] + xg1;
        float ao = a_s[2][s_idx][jl] + xg2;
        float ag = a_s[3][s_idx][jl] + xg3;
        float ig = 1.f/(1.f + __expf(-ai));
        float fg = 1.f/(1.f + __expf(-af));
        float og = 1.f/(1.f + __expf(-ao));
        float gg = tanhf(ag);
        c_r = fg*c_r + ig*gg;
        float hv = og * tanhf(c_r);
        unsigned short hb = f2bf(hv);
        hw[s_idx*HIDDEN + w*16 + jl] = hb;    // critical-path h exchange
        // ---- grid barrier ----
        __threadfence();    // release: drain stores + L2 writeback (h -> LLC)
        __syncthreads();
        if (tid == 0){
            unsigned old = atomicAdd((unsigned*)bar, 1u);
            if (old == (unsigned)(NWG*(t+1)) - 1u){
                // all h already LLC-visible (each WG fenced before its add)
                __hip_atomic_store(flag, t+1, __ATOMIC_RELAXED, __HIP_MEMORY_SCOPE_AGENT);
            } else {
                // RELAXED poll: reads coherence point, emits NO buffer_inv
                while (__hip_atomic_load(flag, __ATOMIC_RELAXED, __HIP_MEMORY_SCOPE_AGENT) < t+1)
                    __builtin_amdgcn_s_sleep(2);
            }
        }
        __syncthreads();
        __threadfence();    // acquire: ONE L1/L2 invalidate before reading others' h
        // hs store off the critical path: drains during next step's MFMA phase
        hs[((long)s_idx*TSTEPS + t)*HIDDEN + w*16 + jl] = hb;
    }
}

// ---------------------------------------------------------------- K3:
// Fused vocab GEMM + per-row softmax partials. BM=64, BN=256, 256 thr (4 waves).
// A = hs bf16 [4096][512], B = WvT bf16 [32000][512] (B^T layout, m91-verified).
__global__ __launch_bounds__(256) void vocab_gemm(const unsigned short* __restrict__ hs,
        const unsigned short* __restrict__ WvT, const float* __restrict__ bvoc,
        const int* __restrict__ captions, float* __restrict__ pmax,
        float* __restrict__ psum, float* __restrict__ tlog){
    int bn = blockIdx.x;    // 0..124
    int bm = blockIdx.y;    // 0..63
    int tid = threadIdx.x;
    int wv = tid >> 6, L = tid & 63;
    int q = L >> 4, ln = L & 15;
    __shared__ int   tgt_s[64];
    __shared__ float wmax_s[4][64], wsum_s[4][64];
    if (tid < 64){
        int rg = bm*64 + tid;
        tgt_s[tid] = captions[(rg >> 8)*257 + (rg & 255) + 1];
    }
    __syncthreads();
    f32x4 acc[4][4];
    for (int mt=0;mt<4;++mt) for (int nt=0;nt<4;++nt) acc[mt][nt] = (f32x4){0.f,0.f,0.f,0.f};
    int colb = bn*256 + wv*64;
    for (int kt = 0; kt < 16; ++kt){
        short8 a[4], bb[4];
        #pragma unroll
        for (int mt=0;mt<4;++mt){
            int row = bm*64 + mt*16 + ln;
            a[mt] = *(const short8*)(hs + (long)row*HIDDEN + kt*32 + q*8);
        }
        #pragma unroll
        for (int nt=0;nt<4;++nt){
            int v = colb + nt*16 + ln;
            bb[nt] = *(const short8*)(WvT + (long)v*HIDDEN + kt*32 + q*8);
        }
        #pragma unroll
        for (int mt=0;mt<4;++mt)
            #pragma unroll
            for (int nt=0;nt<4;++nt)
                acc[mt][nt] = __builtin_amdgcn_mfma_f32_16x16x32_bf16(a[mt], bb[nt], acc[mt][nt], 0,0,0);
    }
    float bv[4];
    #pragma unroll
    for (int nt=0;nt<4;++nt) bv[nt] = bvoc[colb + nt*16 + ln];
    #pragma unroll
    for (int mt=0;mt<4;++mt) for (int nt=0;nt<4;++nt) for (int r=0;r<4;++r)
        acc[mt][nt][r] += bv[nt];
    // target-logit grab (exactly one lane grid-wide matches per row)
    #pragma unroll
    for (int mt=0;mt<4;++mt) for (int r=0;r<4;++r){
        int rl = mt*16 + q*4 + r;
        int tg = tgt_s[rl] - colb;
        if (tg >= 0 && tg < 64){
            int nt = tg >> 4;
            if ((tg & 15) == ln) tlog[bm*64 + rl] = acc[mt][nt][r];
        }
    }
    // per-row max & sumexp over this block's 256 cols
    #pragma unroll
    for (int mt=0;mt<4;++mt){
        #pragma unroll
        for (int r=0;r<4;++r){
            float m = fmaxf(fmaxf(acc[mt][0][r],acc[mt][1][r]), fmaxf(acc[mt][2][r],acc[mt][3][r]));
            for (int d=1; d<16; d<<=1) m = fmaxf(m, __shfl_xor(m, d, 16));
            float s = __expf(acc[mt][0][r]-m) + __expf(acc[mt][1][r]-m)
                    + __expf(acc[mt][2][r]-m) + __expf(acc[mt][3][r]-m);
            for (int d=1; d<16; d<<=1) s += __shfl_xor(s, d, 16);
            if (ln == 0){ int rl = mt*16 + q*4 + r; wmax_s[wv][rl] = m; wsum_s[wv][rl] = s; }
        }
    }
    __syncthreads();
    if (tid < 64){
        float M = fmaxf(fmaxf(wmax_s[0][tid],wmax_s[1][tid]), fmaxf(wmax_s[2][tid],wmax_s[3][tid]));
        float S = 0.f;
        for (int ww=0; ww<4; ++ww) S += wsum_s[ww][tid]*__expf(wmax_s[ww][tid]-M);
        pmax[(long)bn*NROWS + bm*64 + tid] = M;
        psum[(long)bn*NROWS + bm*64 + tid] = S;
    }
}

// ---------------------------------------------------------------- K4:
// combine 125 partials per row -> lse -> masked NLL -> loss/N
__global__ __launch_bounds__(256) void reduce_loss(const float* __restrict__ pmax,
        const float* __restrict__ psum, const float* __restrict__ tlog,
        const int* __restrict__ captions, float* __restrict__ out){
    int r = blockIdx.x*256 + threadIdx.x;
    float M = -1e30f;
    for (int p=0;p<NVB;++p) M = fmaxf(M, pmax[(long)p*NROWS + r]);
    float S = 0.f;
    for (int p=0;p<NVB;++p) S += psum[(long)p*NROWS + r]*__expf(pmax[(long)p*NROWS + r]-M);
    float lse = M + logf(S);
    float nll = lse - tlog[r];
    int tok = captions[(r >> 8)*257 + (r & 255) + 1];
    float val = (tok != 0) ? nll : 0.f;
    __shared__ float red[256];
    red[threadIdx.x] = val; __syncthreads();
    for (int s=128; s>0; s>>=1){
        if (threadIdx.x < s) red[threadIdx.x] += red[threadIdx.x+s];
        __syncthreads();
    }
    if (threadIdx.x == 0) atomicAdd(out, red[0] * (1.0f/16.0f));
}

// ---------------------------------------------------------------- launch
extern "C" void kernel_launch(void* const* d_in, const int* in_sizes, int n_in,
                              void* d_out, int out_size, void* d_ws, size_t ws_size,
                              hipStream_t stream){
    const int*   captions = (const int*)  d_in[0];
    const float* Wemb     = (const float*)d_in[1];
    const float* Wx       = (const float*)d_in[2];
    const float* Wh       = (const float*)d_in[3];
    const float* b        = (const float*)d_in[4];
    const float* Wv       = (const float*)d_in[5];
    const float* bvoc     = (const float*)d_in[6];
    const float* h_init   = (const float*)d_in[7];

    char* ws = (char*)d_ws;
    float*          xw   = (float*)         (ws + 0);          // 33554432 B
    unsigned short* WvT  = (unsigned short*)(ws + 33554432);   // 32768000 B
    unsigned short* hs   = (unsigned short*)(ws + 66322432);   //  4194304 B
    float*          pmax = (float*)         (ws + 70516736);   //  2048000 B
    float*          psum = (float*)         (ws + 72564736);   //  2048000 B
    float*          tlog = (float*)         (ws + 74612736);   //    16384 B
    unsigned short* Whp  = (unsigned short*)(ws + 74629120);   //  2097152 B
    unsigned short* hg   = (unsigned short*)(ws + 76726272);   //    32768 B (2 bufs)
    int*            bar  = (int*)           (ws + 76759040);   //      256 B (counter + flag line)

    float* out_f = (float*)d_out;

    (void)hipMemsetAsync(d_out, 0, sizeof(float), stream);
    (void)hipMemsetAsync(bar, 0, 256, stream);

    hipLaunchKernelGGL(wv_transpose, dim3(500, 8), dim3(256), 0, stream, Wv, WvT);
    hipLaunchKernelGGL(whp_prep,     dim3(NWG),    dim3(256), 0, stream, Wh, Whp);
    hipLaunchKernelGGL(hg_init,      dim3(32),     dim3(256), 0, stream, h_init, hg);
    hipLaunchKernelGGL(embed_xw,     dim3(512),    dim3(256), 0, stream, captions, Wemb, Wx, b, xw);
    hipLaunchKernelGGL(lstm_mfma,    dim3(NWG),    dim3(256), 0, stream, xw, Whp, hg, hs, bar);
    hipLaunchKernelGGL(vocab_gemm,   dim3(NVB,64), dim3(256), 0, stream, hs, WvT, bvoc, captions, pmax, psum, tlog);
    hipLaunchKernelGGL(reduce_loss,  dim3(16),     dim3(256), 0, stream, pmax, psum, tlog, captions, out_f);
}

// Round 5
// 2195.697 us; speedup vs baseline: 1.3857x; 1.2580x over previous
//
#include <hip/hip_runtime.h>

#define VOCAB   32000
#define WORDVEC 256
#define HIDDEN  512
#define TSTEPS  256
#define NBATCH  16
#define NROWS   (TSTEPS*NBATCH)   // 4096
#define GATES   (4*HIDDEN)        // 2048
#define NVB     125               // 32000/256
#define NWG     32                // LSTM workgroups (32 x 16 hidden units)

typedef __attribute__((ext_vector_type(8))) short short8;
typedef __attribute__((ext_vector_type(4))) float f32x4;
typedef unsigned long long u64;

__device__ __forceinline__ unsigned short f2bf(float x){
    union { float f; unsigned int u; } v; v.f = x;
    unsigned int r = v.u + 0x7fffu + ((v.u >> 16) & 1u);
    return (unsigned short)(r >> 16);
}

// ---------------------------------------------------------------- K0a:
// W_vocab (fp32 [512][32000]) -> WvT (bf16 [32000][512]) via LDS transpose
__global__ void wv_transpose(const float* __restrict__ Wv, unsigned short* __restrict__ WvT){
    __shared__ float s[64][65];
    int v0 = blockIdx.x * 64;
    int k0 = blockIdx.y * 64;
    int tid = threadIdx.x;
    for (int i = 0; i < 16; ++i){
        int lin = tid + i*256;
        int kk = lin >> 6, vv = lin & 63;
        s[kk][vv] = Wv[(long)(k0+kk)*VOCAB + v0 + vv];
    }
    __syncthreads();
    for (int i = 0; i < 16; ++i){
        int lin = tid + i*256;
        int vv = lin >> 6, kk = lin & 63;
        WvT[(long)(v0+vv)*HIDDEN + k0 + kk] = f2bf(s[kk][vv]);
    }
}

// ---------------------------------------------------------------- K0b:
// Wh (fp32 [512][2048]) -> Whp: per-WG MFMA-B-fragment-ordered bf16 image.
// WG w owns hidden units w*16..+16. N-tile nt == gate g (cols p = nt*16+ln).
// Fragment f = kt*4+nt (kt<16); lane L holds B[k=kt*32+(L>>4)*8+jj][n=nt*16+(L&15)].
__global__ void whp_prep(const float* __restrict__ Wh, unsigned short* __restrict__ Whp){
    int w = blockIdx.x; int tid = threadIdx.x;   // 32 blocks x 256 thr
    for (int item = tid; item < 4096; item += 256){
        int f = item >> 6;          // 0..63
        int L = item & 63;
        int kt = f >> 2, nt = f & 3;
        int q = L >> 4, ln = L & 15;
        int col = nt*HIDDEN + w*16 + ln;   // gate nt, unit w*16+ln
        short8 vvec;
        for (int jj = 0; jj < 8; ++jj){
            int k = kt*32 + q*8 + jj;
            vvec[jj] = (short)f2bf(Wh[(long)k*GATES + col]);
        }
        *(short8*)(Whp + ((long)w*4096 + item)*8) = vvec;
    }
}

// ---------------------------------------------------------------- K0c:
// broadcast h_init into hglob buffer 0 (bf16, [16][512])
__global__ void hg_init(const float* __restrict__ h_init, unsigned short* __restrict__ hg){
    int idx = blockIdx.x*256 + threadIdx.x;   // 8192
    int j = idx & 511;
    hg[idx] = f2bf(h_init[j]);
}

// ---------------------------------------------------------------- K1:
// xw[r=t*16+n][k] = b[k] + sum_d W_embed[cap_in[n][t]][d] * Wx[d][k]   (fp32)
__global__ __launch_bounds__(256) void embed_xw(const int* __restrict__ captions,
        const float* __restrict__ Wemb, const float* __restrict__ Wx,
        const float* __restrict__ b, float* __restrict__ xw){
    __shared__ float xs[8][WORDVEC];
    __shared__ int toks[8];
    int tid = threadIdx.x;
    int r0 = blockIdx.x * 8;
    if (tid < 8){
        int r = r0 + tid; int t = r >> 4, n = r & 15;
        toks[tid] = captions[n*257 + t];
    }
    __syncthreads();
    for (int i = 0; i < 8; ++i){
        int lin = tid + i*256;
        int ri = lin >> 8, d = lin & 255;
        xs[ri][d] = Wemb[(long)toks[ri]*WORDVEC + d];
    }
    __syncthreads();
    float4 b0 = *(const float4*)(b + tid*4);
    float4 b1 = *(const float4*)(b + 1024 + tid*4);
    float acc[8][8];
    for (int ri = 0; ri < 8; ++ri){
        acc[ri][0]=b0.x; acc[ri][1]=b0.y; acc[ri][2]=b0.z; acc[ri][3]=b0.w;
        acc[ri][4]=b1.x; acc[ri][5]=b1.y; acc[ri][6]=b1.z; acc[ri][7]=b1.w;
    }
    for (int d = 0; d < WORDVEC; ++d){
        float4 w0 = *(const float4*)(Wx + (long)d*GATES + tid*4);
        float4 w1 = *(const float4*)(Wx + (long)d*GATES + 1024 + tid*4);
        #pragma unroll
        for (int ri = 0; ri < 8; ++ri){
            float xv = xs[ri][d];
            acc[ri][0] += xv*w0.x; acc[ri][1] += xv*w0.y;
            acc[ri][2] += xv*w0.z; acc[ri][3] += xv*w0.w;
            acc[ri][4] += xv*w1.x; acc[ri][5] += xv*w1.y;
            acc[ri][6] += xv*w1.z; acc[ri][7] += xv*w1.w;
        }
    }
    for (int ri = 0; ri < 8; ++ri){
        float4 o0 = {acc[ri][0],acc[ri][1],acc[ri][2],acc[ri][3]};
        float4 o1 = {acc[ri][4],acc[ri][5],acc[ri][6],acc[ri][7]};
        *(float4*)(xw + (long)(r0+ri)*GATES + tid*4) = o0;
        *(float4*)(xw + (long)(r0+ri)*GATES + 1024 + tid*4) = o1;
    }
}

// ---------------------------------------------------------------- K2:
// Batched LSTM, fence-free: ALL cross-WG data (h, flags) moves via agent-scope
// RELAXED atomics (sc0 sc1 -> LLC-direct, coherent by construction). No
// __threadfence (no per-step L2 writeback/invalidate walks). Per-WG monotone
// flags on separate cachelines; every wave polls all 32 flags directly.
__global__ __launch_bounds__(256) void lstm_mfma(const float* __restrict__ xw,
        const unsigned short* __restrict__ Whp, u64* __restrict__ hgq,
        unsigned short* __restrict__ hs, int* __restrict__ flags){
    __shared__ unsigned short whs[64*64*8];   // 64 KB
    __shared__ float a_s[4][16][16];          // 4 KB
    int w = blockIdx.x;          // 0..31
    int tid = threadIdx.x;       // 0..255
    int wv = tid >> 6;           // wave = gate = N-tile (0..3)
    int L = tid & 63;
    int q = L >> 4, ln = L & 15;
    { // stage Wh slice
        const int4* src = (const int4*)(Whp + (long)w*4096*8);
        int4* dst = (int4*)whs;
        for (int i = tid; i < 4096; i += 256) dst[i] = src[i];
    }
    int s_idx = tid >> 4, jl = tid & 15;   // (sequence, local hidden unit)
    float c_r = 0.f;
    __syncthreads();
    for (int t = 0; t < TSTEPS; ++t){
        // ---- wait: all WGs published h_t (flags >= t). t=0: h_0 from hg_init.
        if (t > 0 && L < NWG){
            const int* fp = flags + L*32;   // one flag per 128B cacheline
            while (__hip_atomic_load(fp, __ATOMIC_RELAXED, __HIP_MEMORY_SCOPE_AGENT) < t)
                __builtin_amdgcn_s_sleep(1);
        }
        // xw for gate phase (read-only, normal cached loads)
        long xb = (long)(t*16 + s_idx)*GATES + w*16 + jl;
        float xg0 = xw[xb], xg1 = xw[xb+512], xg2 = xw[xb+1024], xg3 = xw[xb+1536];

        const u64* hr = hgq + (t & 1)*2048;        // [16 seq][128 u64]
        u64*       hw = hgq + ((t+1) & 1)*2048;

        // ---- load full h (16KB) as relaxed-atomic u64 (LLC-direct, coherent)
        u64 hu[32];
        #pragma unroll
        for (int kt = 0; kt < 16; ++kt){
            int base = ln*128 + kt*8 + q*2;
            hu[2*kt]   = __hip_atomic_load(hr + base,     __ATOMIC_RELAXED, __HIP_MEMORY_SCOPE_AGENT);
            hu[2*kt+1] = __hip_atomic_load(hr + base + 1, __ATOMIC_RELAXED, __HIP_MEMORY_SCOPE_AGENT);
        }
        f32x4 acc = {0.f,0.f,0.f,0.f};
        #pragma unroll
        for (int kt = 0; kt < 16; ++kt){
            union { u64 u[2]; short8 v; } cvt;
            cvt.u[0] = hu[2*kt]; cvt.u[1] = hu[2*kt+1];
            short8 bf = *(const short8*)(whs + ((kt*4 + wv)*64 + L)*8);
            acc = __builtin_amdgcn_mfma_f32_16x16x32_bf16(cvt.v, bf, acc, 0, 0, 0);
        }
        // D layout: row(seq) = q*4+reg, col(unit) = ln; wave wv = gate
        #pragma unroll
        for (int r = 0; r < 4; ++r) a_s[wv][q*4 + r][ln] = acc[r];
        __syncthreads();
        // gate phase: thread -> (s_idx, jl)
        float ai = a_s[0][s_idx][jl] + xg0;
        float af = a_s[1][s_idx][jl] + xg1;
        float ao = a_s[2][s_idx][jl] + xg2;
        float ag = a_s[3][s_idx][jl] + xg3;
        float ig = 1.f/(1.f + __expf(-ai));
        float fg = 1.f/(1.f + __expf(-af));
        float og = 1.f/(1.f + __expf(-ao));
        float gg = tanhf(ag);
        c_r = fg*c_r + ig*gg;
        float hv = og * tanhf(c_r);
        unsigned short hb = f2bf(hv);
        // ---- publish h slice: pack 4 bf16 (jl groups of 4) -> u64, atomic store
        int hv32 = (int)hb;
        int base4 = L & ~3;
        u64 pk =  (u64)(unsigned short)__shfl(hv32, base4)
               | ((u64)(unsigned short)__shfl(hv32, base4+1) << 16)
               | ((u64)(unsigned short)__shfl(hv32, base4+2) << 32)
               | ((u64)(unsigned short)__shfl(hv32, base4+3) << 48);
        if ((L & 3) == 0){
            int colu = (w*16 + jl) >> 2;   // u64 col index, jl%4==0 here
            __hip_atomic_store(hw + s_idx*128 + colu, pk, __ATOMIC_RELAXED, __HIP_MEMORY_SCOPE_AGENT);
        }
        // stores acked by LLC before barrier exit (per-wave vmcnt drain)
        __asm__ __volatile__("s_waitcnt vmcnt(0)" ::: "memory");
        __syncthreads();
        if (tid == 0)
            __hip_atomic_store(flags + w*32, t+1, __ATOMIC_RELAXED, __HIP_MEMORY_SCOPE_AGENT);
        // hs history store off critical path (plain cached; visible at kernel end)
        hs[((long)s_idx*TSTEPS + t)*HIDDEN + w*16 + jl] = hb;
    }
}

// ---------------------------------------------------------------- K3:
// Fused vocab GEMM + per-row softmax partials. BM=64, BN=256, 256 thr (4 waves).
// A = hs bf16 [4096][512], B = WvT bf16 [32000][512] (B^T layout, m91-verified).
__global__ __launch_bounds__(256) void vocab_gemm(const unsigned short* __restrict__ hs,
        const unsigned short* __restrict__ WvT, const float* __restrict__ bvoc,
        const int* __restrict__ captions, float* __restrict__ pmax,
        float* __restrict__ psum, float* __restrict__ tlog){
    int bn = blockIdx.x;    // 0..124
    int bm = blockIdx.y;    // 0..63
    int tid = threadIdx.x;
    int wv = tid >> 6, L = tid & 63;
    int q = L >> 4, ln = L & 15;
    __shared__ int   tgt_s[64];
    __shared__ float wmax_s[4][64], wsum_s[4][64];
    if (tid < 64){
        int rg = bm*64 + tid;
        tgt_s[tid] = captions[(rg >> 8)*257 + (rg & 255) + 1];
    }
    __syncthreads();
    f32x4 acc[4][4];
    for (int mt=0;mt<4;++mt) for (int nt=0;nt<4;++nt) acc[mt][nt] = (f32x4){0.f,0.f,0.f,0.f};
    int colb = bn*256 + wv*64;
    for (int kt = 0; kt < 16; ++kt){
        short8 a[4], bb[4];
        #pragma unroll
        for (int mt=0;mt<4;++mt){
            int row = bm*64 + mt*16 + ln;
            a[mt] = *(const short8*)(hs + (long)row*HIDDEN + kt*32 + q*8);
        }
        #pragma unroll
        for (int nt=0;nt<4;++nt){
            int v = colb + nt*16 + ln;
            bb[nt] = *(const short8*)(WvT + (long)v*HIDDEN + kt*32 + q*8);
        }
        #pragma unroll
        for (int mt=0;mt<4;++mt)
            #pragma unroll
            for (int nt=0;nt<4;++nt)
                acc[mt][nt] = __builtin_amdgcn_mfma_f32_16x16x32_bf16(a[mt], bb[nt], acc[mt][nt], 0,0,0);
    }
    float bv[4];
    #pragma unroll
    for (int nt=0;nt<4;++nt) bv[nt] = bvoc[colb + nt*16 + ln];
    #pragma unroll
    for (int mt=0;mt<4;++mt) for (int nt=0;nt<4;++nt) for (int r=0;r<4;++r)
        acc[mt][nt][r] += bv[nt];
    // target-logit grab (exactly one lane grid-wide matches per row)
    #pragma unroll
    for (int mt=0;mt<4;++mt) for (int r=0;r<4;++r){
        int rl = mt*16 + q*4 + r;
        int tg = tgt_s[rl] - colb;
        if (tg >= 0 && tg < 64){
            int nt = tg >> 4;
            if ((tg & 15) == ln) tlog[bm*64 + rl] = acc[mt][nt][r];
        }
    }
    // per-row max & sumexp over this block's 256 cols
    #pragma unroll
    for (int mt=0;mt<4;++mt){
        #pragma unroll
        for (int r=0;r<4;++r){
            float m = fmaxf(fmaxf(acc[mt][0][r],acc[mt][1][r]), fmaxf(acc[mt][2][r],acc[mt][3][r]));
            for (int d=1; d<16; d<<=1) m = fmaxf(m, __shfl_xor(m, d, 16));
            float s = __expf(acc[mt][0][r]-m) + __expf(acc[mt][1][r]-m)
                    + __expf(acc[mt][2][r]-m) + __expf(acc[mt][3][r]-m);
            for (int d=1; d<16; d<<=1) s += __shfl_xor(s, d, 16);
            if (ln == 0){ int rl = mt*16 + q*4 + r; wmax_s[wv][rl] = m; wsum_s[wv][rl] = s; }
        }
    }
    __syncthreads();
    if (tid < 64){
        float M = fmaxf(fmaxf(wmax_s[0][tid],wmax_s[1][tid]), fmaxf(wmax_s[2][tid],wmax_s[3][tid]));
        float S = 0.f;
        for (int ww=0; ww<4; ++ww) S += wsum_s[ww][tid]*__expf(wmax_s[ww][tid]-M);
        pmax[(long)bn*NROWS + bm*64 + tid] = M;
        psum[(long)bn*NROWS + bm*64 + tid] = S;
    }
}

// ---------------------------------------------------------------- K4:
// combine 125 partials per row -> lse -> masked NLL -> loss/N
__global__ __launch_bounds__(256) void reduce_loss(const float* __restrict__ pmax,
        const float* __restrict__ psum, const float* __restrict__ tlog,
        const int* __restrict__ captions, float* __restrict__ out){
    int r = blockIdx.x*256 + threadIdx.x;
    float M = -1e30f;
    for (int p=0;p<NVB;++p) M = fmaxf(M, pmax[(long)p*NROWS + r]);
    float S = 0.f;
    for (int p=0;p<NVB;++p) S += psum[(long)p*NROWS + r]*__expf(pmax[(long)p*NROWS + r]-M);
    float lse = M + logf(S);
    float nll = lse - tlog[r];
    int tok = captions[(r >> 8)*257 + (r & 255) + 1];
    float val = (tok != 0) ? nll : 0.f;
    __shared__ float red[256];
    red[threadIdx.x] = val; __syncthreads();
    for (int s=128; s>0; s>>=1){
        if (threadIdx.x < s) red[threadIdx.x] += red[threadIdx.x+s];
        __syncthreads();
    }
    if (threadIdx.x == 0) atomicAdd(out, red[0] * (1.0f/16.0f));
}

// ---------------------------------------------------------------- launch
extern "C" void kernel_launch(void* const* d_in, const int* in_sizes, int n_in,
                              void* d_out, int out_size, void* d_ws, size_t ws_size,
                              hipStream_t stream){
    const int*   captions = (const int*)  d_in[0];
    const float* Wemb     = (const float*)d_in[1];
    const float* Wx       = (const float*)d_in[2];
    const float* Wh       = (const float*)d_in[3];
    const float* b        = (const float*)d_in[4];
    const float* Wv       = (const float*)d_in[5];
    const float* bvoc     = (const float*)d_in[6];
    const float* h_init   = (const float*)d_in[7];

    char* ws = (char*)d_ws;
    float*          xw   = (float*)         (ws + 0);          // 33554432 B
    unsigned short* WvT  = (unsigned short*)(ws + 33554432);   // 32768000 B
    unsigned short* hs   = (unsigned short*)(ws + 66322432);   //  4194304 B
    float*          pmax = (float*)         (ws + 70516736);   //  2048000 B
    float*          psum = (float*)         (ws + 72564736);   //  2048000 B
    float*          tlog = (float*)         (ws + 74612736);   //    16384 B
    unsigned short* Whp  = (unsigned short*)(ws + 74629120);   //  2097152 B
    u64*            hgq  = (u64*)           (ws + 76726272);   //    32768 B (2 bufs, u64 view)
    int*            flags= (int*)           (ws + 76759040);   //     4096 B (32 x 128B lines)

    float* out_f = (float*)d_out;

    (void)hipMemsetAsync(d_out, 0, sizeof(float), stream);
    (void)hipMemsetAsync(flags, 0, 4096, stream);

    hipLaunchKernelGGL(wv_transpose, dim3(500, 8), dim3(256), 0, stream, Wv, WvT);
    hipLaunchKernelGGL(whp_prep,     dim3(NWG),    dim3(256), 0, stream, Wh, Whp);
    hipLaunchKernelGGL(hg_init,      dim3(32),     dim3(256), 0, stream, h_init, (unsigned short*)hgq);
    hipLaunchKernelGGL(embed_xw,     dim3(512),    dim3(256), 0, stream, captions, Wemb, Wx, b, xw);
    hipLaunchKernelGGL(lstm_mfma,    dim3(NWG),    dim3(256), 0, stream, xw, Whp, hgq, hs, flags);
    hipLaunchKernelGGL(vocab_gemm,   dim3(NVB,64), dim3(256), 0, stream, hs, WvT, bvoc, captions, pmax, psum, tlog);
    hipLaunchKernelGGL(reduce_loss,  dim3(16),     dim3(256), 0, stream, pmax, psum, tlog, captions, out_f);
}

// Round 6
// 1871.684 us; speedup vs baseline: 1.6255x; 1.1731x over previous
//
#include <hip/hip_runtime.h>

#define VOCAB   32000
#define WORDVEC 256
#define HIDDEN  512
#define TSTEPS  256
#define NBATCH  16
#define NROWS   (TSTEPS*NBATCH)   // 4096
#define GATES   (4*HIDDEN)        // 2048
#define NVB     125               // 32000/256
#define NWG     32                // LSTM workgroups (32 x 16 hidden units)

typedef __attribute__((ext_vector_type(8))) short short8;
typedef __attribute__((ext_vector_type(4))) float f32x4;
typedef unsigned long long u64;

__device__ __forceinline__ unsigned short f2bf(float x){
    union { float f; unsigned int u; } v; v.f = x;
    unsigned int r = v.u + 0x7fffu + ((v.u >> 16) & 1u);
    return (unsigned short)(r >> 16);
}

// ---------------------------------------------------------------- K0a:
// W_vocab (fp32 [512][32000]) -> WvT (bf16 [32000][512]) via LDS transpose
__global__ void wv_transpose(const float* __restrict__ Wv, unsigned short* __restrict__ WvT){
    __shared__ float s[64][65];
    int v0 = blockIdx.x * 64;
    int k0 = blockIdx.y * 64;
    int tid = threadIdx.x;
    for (int i = 0; i < 16; ++i){
        int lin = tid + i*256;
        int kk = lin >> 6, vv = lin & 63;
        s[kk][vv] = Wv[(long)(k0+kk)*VOCAB + v0 + vv];
    }
    __syncthreads();
    for (int i = 0; i < 16; ++i){
        int lin = tid + i*256;
        int vv = lin >> 6, kk = lin & 63;
        WvT[(long)(v0+vv)*HIDDEN + k0 + kk] = f2bf(s[kk][vv]);
    }
}

// ---------------------------------------------------------------- K0b:
// Wh (fp32 [512][2048]) -> Whp: per-WG MFMA-B-fragment-ordered bf16 image.
// WG w owns hidden units w*16..+16. N-tile nt == gate g (cols p = nt*16+ln).
// Fragment f = kt*4+nt (kt<16); lane L holds B[k=kt*32+(L>>4)*8+jj][n=nt*16+(L&15)].
__global__ void whp_prep(const float* __restrict__ Wh, unsigned short* __restrict__ Whp){
    int w = blockIdx.x; int tid = threadIdx.x;   // 32 blocks x 256 thr
    for (int item = tid; item < 4096; item += 256){
        int f = item >> 6;          // 0..63
        int L = item & 63;
        int kt = f >> 2, nt = f & 3;
        int q = L >> 4, ln = L & 15;
        int col = nt*HIDDEN + w*16 + ln;   // gate nt, unit w*16+ln
        short8 vvec;
        for (int jj = 0; jj < 8; ++jj){
            int k = kt*32 + q*8 + jj;
            vvec[jj] = (short)f2bf(Wh[(long)k*GATES + col]);
        }
        *(short8*)(Whp + ((long)w*4096 + item)*8) = vvec;
    }
}

// ---------------------------------------------------------------- K0c:
// h_init broadcast into h buffer 0, FRAGMENT-LINEAR layout:
// elem e -> j = e&7, seq = (e>>3)&15, fq = e>>7 (kt*4+q); unit = (fq>>2)*32+(fq&3)*8+j
__global__ void hg_init(const float* __restrict__ h_init, unsigned short* __restrict__ hg){
    int e = blockIdx.x*256 + threadIdx.x;   // 8192
    int j = e & 7, fq = e >> 7;
    int unit = (fq>>2)*32 + (fq&3)*8 + j;
    hg[e] = f2bf(h_init[unit]);
}

// ---------------------------------------------------------------- K1:
// xw[r=t*16+n][k] = b[k] + sum_d W_embed[cap_in[n][t]][d] * Wx[d][k]   (fp32)
__global__ __launch_bounds__(256) void embed_xw(const int* __restrict__ captions,
        const float* __restrict__ Wemb, const float* __restrict__ Wx,
        const float* __restrict__ b, float* __restrict__ xw){
    __shared__ float xs[8][WORDVEC];
    __shared__ int toks[8];
    int tid = threadIdx.x;
    int r0 = blockIdx.x * 8;
    if (tid < 8){
        int r = r0 + tid; int t = r >> 4, n = r & 15;
        toks[tid] = captions[n*257 + t];
    }
    __syncthreads();
    for (int i = 0; i < 8; ++i){
        int lin = tid + i*256;
        int ri = lin >> 8, d = lin & 255;
        xs[ri][d] = Wemb[(long)toks[ri]*WORDVEC + d];
    }
    __syncthreads();
    float4 b0 = *(const float4*)(b + tid*4);
    float4 b1 = *(const float4*)(b + 1024 + tid*4);
    float acc[8][8];
    for (int ri = 0; ri < 8; ++ri){
        acc[ri][0]=b0.x; acc[ri][1]=b0.y; acc[ri][2]=b0.z; acc[ri][3]=b0.w;
        acc[ri][4]=b1.x; acc[ri][5]=b1.y; acc[ri][6]=b1.z; acc[ri][7]=b1.w;
    }
    for (int d = 0; d < WORDVEC; ++d){
        float4 w0 = *(const float4*)(Wx + (long)d*GATES + tid*4);
        float4 w1 = *(const float4*)(Wx + (long)d*GATES + 1024 + tid*4);
        #pragma unroll
        for (int ri = 0; ri < 8; ++ri){
            float xv = xs[ri][d];
            acc[ri][0] += xv*w0.x; acc[ri][1] += xv*w0.y;
            acc[ri][2] += xv*w0.z; acc[ri][3] += xv*w0.w;
            acc[ri][4] += xv*w1.x; acc[ri][5] += xv*w1.y;
            acc[ri][6] += xv*w1.z; acc[ri][7] += xv*w1.w;
        }
    }
    for (int ri = 0; ri < 8; ++ri){
        float4 o0 = {acc[ri][0],acc[ri][1],acc[ri][2],acc[ri][3]};
        float4 o1 = {acc[ri][4],acc[ri][5],acc[ri][6],acc[ri][7]};
        *(float4*)(xw + (long)(r0+ri)*GATES + tid*4) = o0;
        *(float4*)(xw + (long)(r0+ri)*GATES + 1024 + tid*4) = o1;
    }
}

// ---------------------------------------------------------------- K2:
// Batched LSTM, fence-free. Per step:
//   poll flags (xw loads hoisted above) -> coalesced stage h (LLC->LDS, once
//   per WG) -> MFMA with Wh B-fragments IN REGISTERS -> gates -> publish h
//   (fragment-linear, relaxed agent atomics) -> flag.
__global__ __launch_bounds__(256) void lstm_mfma(const float* __restrict__ xw,
        const unsigned short* __restrict__ Whp, u64* __restrict__ hgq,
        unsigned short* __restrict__ hs, int* __restrict__ flags){
    __shared__ u64 hstage[2048];          // 16 KB, fragment-linear h_t
    __shared__ float a_s[4][16][16];      // 4 KB
    int w = blockIdx.x;          // 0..31
    int tid = threadIdx.x;       // 0..255
    int wv = tid >> 6;           // wave = gate = N-tile (0..3)
    int L = tid & 63;
    int q = L >> 4, ln = L & 15;
    int s_idx = tid >> 4, jl = tid & 15;   // (sequence, local hidden unit)

    // Wh B-fragments -> registers (wave wv uses fragments kt*4+wv only)
    short8 bw[16];
    #pragma unroll
    for (int kt = 0; kt < 16; ++kt)
        bw[kt] = *(const short8*)(Whp + ((long)w*4096 + (kt*4+wv)*64 + L)*8);

    float c_r = 0.f;
    // publish u64 index (thread with jl%4==0 stores for jl..jl+3)
    int fq_pub = (w>>1)*4 + (w&1)*2 + (jl>>3);
    int pubIdx = (fq_pub*16 + s_idx)*2 + ((jl&7)>>2);
    int abase = (q*16 + ln)*2;   // u64 idx of (kt=0,q,ln)

    for (int t = 0; t < TSTEPS; ++t){
        // xw loads first: HBM latency overlaps the flag wait
        long xb = (long)(t*16 + s_idx)*GATES + w*16 + jl;
        float xg0 = xw[xb], xg1 = xw[xb+512], xg2 = xw[xb+1024], xg3 = xw[xb+1536];

        // wait: all WGs published h_t (flags >= t). t=0: h_0 from hg_init.
        if (t > 0 && L < NWG){
            const int* fp = flags + L*32;   // one flag per 128B line
            while (__hip_atomic_load(fp, __ATOMIC_RELAXED, __HIP_MEMORY_SCOPE_AGENT) < t)
                __builtin_amdgcn_s_sleep(1);
        }

        const u64* hr = hgq + (t & 1)*2048;
        u64*       hw = hgq + ((t+1) & 1)*2048;

        // stage h_t: 2048 u64, coalesced (8 per thread), LLC-direct
        #pragma unroll
        for (int i = 0; i < 8; ++i){
            int idx = tid + i*256;
            hstage[idx] = __hip_atomic_load(hr + idx, __ATOMIC_RELAXED, __HIP_MEMORY_SCOPE_AGENT);
        }
        __syncthreads();   // S1: stage complete

        f32x4 acc = {0.f,0.f,0.f,0.f};
        #pragma unroll
        for (int kt = 0; kt < 16; ++kt){
            short8 a = *(const short8*)((const unsigned short*)hstage + (kt*128 + abase)*4);
            acc = __builtin_amdgcn_mfma_f32_16x16x32_bf16(a, bw[kt], acc, 0, 0, 0);
        }
        // D layout: row(seq) = q*4+reg, col(unit) = ln; wave wv = gate
        #pragma unroll
        for (int r = 0; r < 4; ++r) a_s[wv][q*4 + r][ln] = acc[r];
        __syncthreads();   // S2: a_s complete (also: all hstage reads done)

        // gate phase: thread -> (s_idx, jl)
        float ai = a_s[0][s_idx][jl] + xg0;
        float af = a_s[1][s_idx][jl] + xg1;
        float ao = a_s[2][s_idx][jl] + xg2;
        float ag = a_s[3][s_idx][jl] + xg3;
        float ig = 1.f/(1.f + __expf(-ai));
        float fg = 1.f/(1.f + __expf(-af));
        float og = 1.f/(1.f + __expf(-ao));
        float gg = tanhf(ag);
        c_r = fg*c_r + ig*gg;
        float hv = og * tanhf(c_r);
        unsigned short hb = f2bf(hv);

        // publish h slice: pack 4 bf16 -> u64, relaxed agent store (LLC-direct)
        int hv32 = (int)hb;
        int base4 = L & ~3;
        u64 pk =  (u64)(unsigned short)__shfl(hv32, base4)
               | ((u64)(unsigned short)__shfl(hv32, base4+1) << 16)
               | ((u64)(unsigned short)__shfl(hv32, base4+2) << 32)
               | ((u64)(unsigned short)__shfl(hv32, base4+3) << 48);
        if ((tid & 3) == 0)
            __hip_atomic_store(hw + pubIdx, pk, __ATOMIC_RELAXED, __HIP_MEMORY_SCOPE_AGENT);
        __asm__ __volatile__("s_waitcnt vmcnt(0)" ::: "memory");
        __syncthreads();   // S3: all publishes acked
        if (tid == 0)
            __hip_atomic_store(flags + w*32, t+1, __ATOMIC_RELAXED, __HIP_MEMORY_SCOPE_AGENT);
        // hs history store off critical path (plain cached)
        hs[((long)s_idx*TSTEPS + t)*HIDDEN + w*16 + jl] = hb;
    }
}

// ---------------------------------------------------------------- K3:
// Fused vocab GEMM + per-row softmax partials. BM=64, BN=256, 256 thr (4 waves).
// A = hs bf16 [4096][512], B = WvT bf16 [32000][512] (B^T layout, m91-verified).
__global__ __launch_bounds__(256) void vocab_gemm(const unsigned short* __restrict__ hs,
        const unsigned short* __restrict__ WvT, const float* __restrict__ bvoc,
        const int* __restrict__ captions, float* __restrict__ pmax,
        float* __restrict__ psum, float* __restrict__ tlog){
    int bn = blockIdx.x;    // 0..124
    int bm = blockIdx.y;    // 0..63
    int tid = threadIdx.x;
    int wv = tid >> 6, L = tid & 63;
    int q = L >> 4, ln = L & 15;
    __shared__ int   tgt_s[64];
    __shared__ float wmax_s[4][64], wsum_s[4][64];
    if (tid < 64){
        int rg = bm*64 + tid;
        tgt_s[tid] = captions[(rg >> 8)*257 + (rg & 255) + 1];
    }
    __syncthreads();
    f32x4 acc[4][4];
    for (int mt=0;mt<4;++mt) for (int nt=0;nt<4;++nt) acc[mt][nt] = (f32x4){0.f,0.f,0.f,0.f};
    int colb = bn*256 + wv*64;
    for (int kt = 0; kt < 16; ++kt){
        short8 a[4], bb[4];
        #pragma unroll
        for (int mt=0;mt<4;++mt){
            int row = bm*64 + mt*16 + ln;
            a[mt] = *(const short8*)(hs + (long)row*HIDDEN + kt*32 + q*8);
        }
        #pragma unroll
        for (int nt=0;nt<4;++nt){
            int v = colb + nt*16 + ln;
            bb[nt] = *(const short8*)(WvT + (long)v*HIDDEN + kt*32 + q*8);
        }
        #pragma unroll
        for (int mt=0;mt<4;++mt)
            #pragma unroll
            for (int nt=0;nt<4;++nt)
                acc[mt][nt] = __builtin_amdgcn_mfma_f32_16x16x32_bf16(a[mt], bb[nt], acc[mt][nt], 0,0,0);
    }
    float bv[4];
    #pragma unroll
    for (int nt=0;nt<4;++nt) bv[nt] = bvoc[colb + nt*16 + ln];
    #pragma unroll
    for (int mt=0;mt<4;++mt) for (int nt=0;nt<4;++nt) for (int r=0;r<4;++r)
        acc[mt][nt][r] += bv[nt];
    // target-logit grab (exactly one lane grid-wide matches per row)
    #pragma unroll
    for (int mt=0;mt<4;++mt) for (int r=0;r<4;++r){
        int rl = mt*16 + q*4 + r;
        int tg = tgt_s[rl] - colb;
        if (tg >= 0 && tg < 64){
            int nt = tg >> 4;
            if ((tg & 15) == ln) tlog[bm*64 + rl] = acc[mt][nt][r];
        }
    }
    // per-row max & sumexp over this block's 256 cols
    #pragma unroll
    for (int mt=0;mt<4;++mt){
        #pragma unroll
        for (int r=0;r<4;++r){
            float m = fmaxf(fmaxf(acc[mt][0][r],acc[mt][1][r]), fmaxf(acc[mt][2][r],acc[mt][3][r]));
            for (int d=1; d<16; d<<=1) m = fmaxf(m, __shfl_xor(m, d, 16));
            float s = __expf(acc[mt][0][r]-m) + __expf(acc[mt][1][r]-m)
                    + __expf(acc[mt][2][r]-m) + __expf(acc[mt][3][r]-m);
            for (int d=1; d<16; d<<=1) s += __shfl_xor(s, d, 16);
            if (ln == 0){ int rl = mt*16 + q*4 + r; wmax_s[wv][rl] = m; wsum_s[wv][rl] = s; }
        }
    }
    __syncthreads();
    if (tid < 64){
        float M = fmaxf(fmaxf(wmax_s[0][tid],wmax_s[1][tid]), fmaxf(wmax_s[2][tid],wmax_s[3][tid]));
        float S = 0.f;
        for (int ww=0; ww<4; ++ww) S += wsum_s[ww][tid]*__expf(wmax_s[ww][tid]-M);
        pmax[(long)bn*NROWS + bm*64 + tid] = M;
        psum[(long)bn*NROWS + bm*64 + tid] = S;
    }
}

// ---------------------------------------------------------------- K4:
// combine 125 partials per row -> lse -> masked NLL -> loss/N
__global__ __launch_bounds__(256) void reduce_loss(const float* __restrict__ pmax,
        const float* __restrict__ psum, const float* __restrict__ tlog,
        const int* __restrict__ captions, float* __restrict__ out){
    int r = blockIdx.x*256 + threadIdx.x;
    float M = -1e30f;
    for (int p=0;p<NVB;++p) M = fmaxf(M, pmax[(long)p*NROWS + r]);
    float S = 0.f;
    for (int p=0;p<NVB;++p) S += psum[(long)p*NROWS + r]*__expf(pmax[(long)p*NROWS + r]-M);
    float lse = M + logf(S);
    float nll = lse - tlog[r];
    int tok = captions[(r >> 8)*257 + (r & 255) + 1];
    float val = (tok != 0) ? nll : 0.f;
    __shared__ float red[256];
    red[threadIdx.x] = val; __syncthreads();
    for (int s=128; s>0; s>>=1){
        if (threadIdx.x < s) red[threadIdx.x] += red[threadIdx.x+s];
        __syncthreads();
    }
    if (threadIdx.x == 0) atomicAdd(out, red[0] * (1.0f/16.0f));
}

// ---------------------------------------------------------------- launch
extern "C" void kernel_launch(void* const* d_in, const int* in_sizes, int n_in,
                              void* d_out, int out_size, void* d_ws, size_t ws_size,
                              hipStream_t stream){
    const int*   captions = (const int*)  d_in[0];
    const float* Wemb     = (const float*)d_in[1];
    const float* Wx       = (const float*)d_in[2];
    const float* Wh       = (const float*)d_in[3];
    const float* b        = (const float*)d_in[4];
    const float* Wv       = (const float*)d_in[5];
    const float* bvoc     = (const float*)d_in[6];
    const float* h_init   = (const float*)d_in[7];

    char* ws = (char*)d_ws;
    float*          xw   = (float*)         (ws + 0);          // 33554432 B
    unsigned short* WvT  = (unsigned short*)(ws + 33554432);   // 32768000 B
    unsigned short* hs   = (unsigned short*)(ws + 66322432);   //  4194304 B
    float*          pmax = (float*)         (ws + 70516736);   //  2048000 B
    float*          psum = (float*)         (ws + 72564736);   //  2048000 B
    float*          tlog = (float*)         (ws + 74612736);   //    16384 B
    unsigned short* Whp  = (unsigned short*)(ws + 74629120);   //  2097152 B
    u64*            hgq  = (u64*)           (ws + 76726272);   //    32768 B (2 bufs, u64 view)
    int*            flags= (int*)           (ws + 76759040);   //     4096 B (32 x 128B lines)

    float* out_f = (float*)d_out;

    (void)hipMemsetAsync(d_out, 0, sizeof(float), stream);
    (void)hipMemsetAsync(flags, 0, 4096, stream);

    hipLaunchKernelGGL(wv_transpose, dim3(500, 8), dim3(256), 0, stream, Wv, WvT);
    hipLaunchKernelGGL(whp_prep,     dim3(NWG),    dim3(256), 0, stream, Wh, Whp);
    hipLaunchKernelGGL(hg_init,      dim3(32),     dim3(256), 0, stream, h_init, (unsigned short*)hgq);
    hipLaunchKernelGGL(embed_xw,     dim3(512),    dim3(256), 0, stream, captions, Wemb, Wx, b, xw);
    hipLaunchKernelGGL(lstm_mfma,    dim3(NWG),    dim3(256), 0, stream, xw, Whp, hgq, hs, flags);
    hipLaunchKernelGGL(vocab_gemm,   dim3(NVB,64), dim3(256), 0, stream, hs, WvT, bvoc, captions, pmax, psum, tlog);
    hipLaunchKernelGGL(reduce_loss,  dim3(16),     dim3(256), 0, stream, pmax, psum, tlog, captions, out_f);
}

// Round 7
// 1414.442 us; speedup vs baseline: 2.1510x; 1.3233x over previous
//
#include <hip/hip_runtime.h>

#define VOCAB   32000
#define WORDVEC 256
#define HIDDEN  512
#define TSTEPS  256
#define NBATCH  16
#define NROWS   (TSTEPS*NBATCH)   // 4096
#define GATES   (4*HIDDEN)        // 2048
#define NVB     125               // 32000/256
#define NWG     32                // LSTM workgroups (32 x 16 hidden units)

typedef __attribute__((ext_vector_type(8))) short short8;
typedef __attribute__((ext_vector_type(4))) float f32x4;
typedef unsigned long long u64;

__device__ __forceinline__ unsigned short f2bf(float x){
    union { float f; unsigned int u; } v; v.f = x;
    unsigned int r = v.u + 0x7fffu + ((v.u >> 16) & 1u);
    return (unsigned short)(r >> 16);
}

// ---------------------------------------------------------------- K0a:
// W_vocab (fp32 [512][32000]) -> WvT (bf16 [32000][512]) via LDS transpose
__global__ void wv_transpose(const float* __restrict__ Wv, unsigned short* __restrict__ WvT){
    __shared__ float s[64][65];
    int v0 = blockIdx.x * 64;
    int k0 = blockIdx.y * 64;
    int tid = threadIdx.x;
    for (int i = 0; i < 16; ++i){
        int lin = tid + i*256;
        int kk = lin >> 6, vv = lin & 63;
        s[kk][vv] = Wv[(long)(k0+kk)*VOCAB + v0 + vv];
    }
    __syncthreads();
    for (int i = 0; i < 16; ++i){
        int lin = tid + i*256;
        int vv = lin >> 6, kk = lin & 63;
        WvT[(long)(v0+vv)*HIDDEN + k0 + kk] = f2bf(s[kk][vv]);
    }
}

// ---------------------------------------------------------------- K0b:
// Wh (fp32 [512][2048]) -> Whp: per-WG MFMA-B-fragment-ordered bf16 image.
// WG w owns hidden units w*16..+16. N-tile nt == gate g (cols p = nt*16+ln).
// Fragment f = kt*4+nt (kt<16); lane L holds B[k=kt*32+(L>>4)*8+jj][n=nt*16+(L&15)].
__global__ void whp_prep(const float* __restrict__ Wh, unsigned short* __restrict__ Whp){
    int w = blockIdx.x; int tid = threadIdx.x;   // 32 blocks x 256 thr
    for (int item = tid; item < 4096; item += 256){
        int f = item >> 6;          // 0..63
        int L = item & 63;
        int kt = f >> 2, nt = f & 3;
        int q = L >> 4, ln = L & 15;
        int col = nt*HIDDEN + w*16 + ln;   // gate nt, unit w*16+ln
        short8 vvec;
        for (int jj = 0; jj < 8; ++jj){
            int k = kt*32 + q*8 + jj;
            vvec[jj] = (short)f2bf(Wh[(long)k*GATES + col]);
        }
        *(short8*)(Whp + ((long)w*4096 + item)*8) = vvec;
    }
}

// ---------------------------------------------------------------- K0c:
// h_0 into exchange buffer 0 as tagged pairs: u64 = {tag=0 | bf16 hi | bf16 lo}.
// Pair p: fq = p>>6 (kt*4+q), s = (p>>2)&15, j = (p&3)*2; unit = (fq>>2)*32+(fq&3)*8+j
__global__ void hg_init(const float* __restrict__ h_init, u64* __restrict__ hx){
    int p = blockIdx.x*256 + threadIdx.x;   // 4096 pairs
    int fq = p >> 6;
    int j  = (p & 3) * 2;
    int u0 = (fq>>2)*32 + (fq&3)*8 + j;
    u64 pk = (u64)f2bf(h_init[u0]) | ((u64)f2bf(h_init[u0+1]) << 16);   // tag 0
    hx[p] = pk;
}

// ---------------------------------------------------------------- K1:
// xw[r=t*16+n][k] = b[k] + sum_d W_embed[cap_in[n][t]][d] * Wx[d][k]   (fp32)
__global__ __launch_bounds__(256) void embed_xw(const int* __restrict__ captions,
        const float* __restrict__ Wemb, const float* __restrict__ Wx,
        const float* __restrict__ b, float* __restrict__ xw){
    __shared__ float xs[8][WORDVEC];
    __shared__ int toks[8];
    int tid = threadIdx.x;
    int r0 = blockIdx.x * 8;
    if (tid < 8){
        int r = r0 + tid; int t = r >> 4, n = r & 15;
        toks[tid] = captions[n*257 + t];
    }
    __syncthreads();
    for (int i = 0; i < 8; ++i){
        int lin = tid + i*256;
        int ri = lin >> 8, d = lin & 255;
        xs[ri][d] = Wemb[(long)toks[ri]*WORDVEC + d];
    }
    __syncthreads();
    float4 b0 = *(const float4*)(b + tid*4);
    float4 b1 = *(const float4*)(b + 1024 + tid*4);
    float acc[8][8];
    for (int ri = 0; ri < 8; ++ri){
        acc[ri][0]=b0.x; acc[ri][1]=b0.y; acc[ri][2]=b0.z; acc[ri][3]=b0.w;
        acc[ri][4]=b1.x; acc[ri][5]=b1.y; acc[ri][6]=b1.z; acc[ri][7]=b1.w;
    }
    for (int d = 0; d < WORDVEC; ++d){
        float4 w0 = *(const float4*)(Wx + (long)d*GATES + tid*4);
        float4 w1 = *(const float4*)(Wx + (long)d*GATES + 1024 + tid*4);
        #pragma unroll
        for (int ri = 0; ri < 8; ++ri){
            float xv = xs[ri][d];
            acc[ri][0] += xv*w0.x; acc[ri][1] += xv*w0.y;
            acc[ri][2] += xv*w0.z; acc[ri][3] += xv*w0.w;
            acc[ri][4] += xv*w1.x; acc[ri][5] += xv*w1.y;
            acc[ri][6] += xv*w1.z; acc[ri][7] += xv*w1.w;
        }
    }
    for (int ri = 0; ri < 8; ++ri){
        float4 o0 = {acc[ri][0],acc[ri][1],acc[ri][2],acc[ri][3]};
        float4 o1 = {acc[ri][4],acc[ri][5],acc[ri][6],acc[ri][7]};
        *(float4*)(xw + (long)(r0+ri)*GATES + tid*4) = o0;
        *(float4*)(xw + (long)(r0+ri)*GATES + 1024 + tid*4) = o1;
    }
}

// ---------------------------------------------------------------- K2:
// Batched LSTM, fence-free + flag-free. h exchanged as TAGGED u64 words
// ({t+1 | 2 bf16}) via relaxed agent atomics: consumers poll the data itself.
// One LLC round-trip per step. Double-buffer proven race-free by the data
// dependency (a WG sees all tag-t words only after all WGs consumed t-1).
__global__ __launch_bounds__(256) void lstm_mfma(const float* __restrict__ xw,
        const unsigned short* __restrict__ Whp, u64* __restrict__ hx,
        unsigned short* __restrict__ hs){
    __shared__ unsigned int hstage[4096];   // 16 KB: h_t as bf16 pairs (tags stripped)
    __shared__ float a_s[4][16][16];        // 4 KB
    int w = blockIdx.x;          // 0..31
    int tid = threadIdx.x;       // 0..255
    int wv = tid >> 6;           // wave = gate = N-tile (0..3)
    int L = tid & 63;
    int q = L >> 4, ln = L & 15;
    int s_idx = tid >> 4, jl = tid & 15;   // (sequence, local hidden unit)

    // Wh B-fragments -> registers (wave wv uses fragments kt*4+wv only)
    short8 bw[16];
    #pragma unroll
    for (int kt = 0; kt < 16; ++kt)
        bw[kt] = *(const short8*)(Whp + ((long)w*4096 + (kt*4+wv)*64 + L)*8);

    float c_r = 0.f;
    // publish pair index: fq for this WG's (jl) + seq + pair-within-8
    int fq_pub = (w>>1)*4 + (w&1)*2 + (jl>>3);
    int pubIdx = fq_pub*64 + s_idx*4 + ((jl>>1)&3);

    for (int t = 0; t < TSTEPS; ++t){
        // xw loads first: HBM latency overlaps the poll
        long xb = (long)(t*16 + s_idx)*GATES + w*16 + jl;
        float xg0 = xw[xb], xg1 = xw[xb+512], xg2 = xw[xb+1024], xg3 = xw[xb+1536];

        const u64* hr = hx + (t & 1)*4096;
        u64*       hw = hx + ((t+1) & 1)*4096;

        // ---- poll + stage: 16 coalesced u64/thread, until all tags == t
        u64 v[16];
        #pragma unroll
        for (int i = 0; i < 16; ++i)
            v[i] = __hip_atomic_load(hr + tid + i*256, __ATOMIC_RELAXED, __HIP_MEMORY_SCOPE_AGENT);
        for (;;){
            u64 bad = 0;
            #pragma unroll
            for (int i = 0; i < 16; ++i) bad |= (v[i] >> 32) ^ (u64)(unsigned)t;
            if (!bad) break;
            __builtin_amdgcn_s_sleep(1);
            #pragma unroll
            for (int i = 0; i < 16; ++i)
                v[i] = __hip_atomic_load(hr + tid + i*256, __ATOMIC_RELAXED, __HIP_MEMORY_SCOPE_AGENT);
        }
        #pragma unroll
        for (int i = 0; i < 16; ++i) hstage[tid + i*256] = (unsigned)v[i];
        __syncthreads();   // S1: stage complete (also orders vs prev a_s reads)

        // ---- MFMA: A-frag (kt,q,ln) = 4 contiguous u32 (linear sweep, 0-conflict)
        f32x4 acc = {0.f,0.f,0.f,0.f};
        #pragma unroll
        for (int kt = 0; kt < 16; ++kt){
            short8 a = *(const short8*)((const unsigned short*)hstage + (kt*256 + q*64 + ln*4)*2);
            acc = __builtin_amdgcn_mfma_f32_16x16x32_bf16(a, bw[kt], acc, 0, 0, 0);
        }
        // D layout: row(seq) = q*4+reg, col(unit) = ln; wave wv = gate
        #pragma unroll
        for (int r = 0; r < 4; ++r) a_s[wv][q*4 + r][ln] = acc[r];
        __syncthreads();   // S2: a_s complete (also: all hstage reads done)

        // ---- gate phase: thread -> (s_idx, jl)
        float ai = a_s[0][s_idx][jl] + xg0;
        float af = a_s[1][s_idx][jl] + xg1;
        float ao = a_s[2][s_idx][jl] + xg2;
        float ag = a_s[3][s_idx][jl] + xg3;
        float ig = 1.f/(1.f + __expf(-ai));
        float fg = 1.f/(1.f + __expf(-af));
        float og = 1.f/(1.f + __expf(-ao));
        float gg = tanhf(ag);
        c_r = fg*c_r + ig*gg;
        float hv = og * tanhf(c_r);
        unsigned short hb = f2bf(hv);

        // ---- publish: pack {tag=t+1 | h[jl+1] | h[jl]}, fire-and-forget
        int hv32 = (int)hb;
        int other = __shfl(hv32, L ^ 1);
        if ((jl & 1) == 0){
            u64 pk = (u64)(unsigned short)hv32
                   | ((u64)(unsigned short)other << 16)
                   | ((u64)(unsigned)(t+1) << 32);
            __hip_atomic_store(hw + pubIdx, pk, __ATOMIC_RELAXED, __HIP_MEMORY_SCOPE_AGENT);
        }
        // hs history store off critical path (plain cached)
        hs[((long)s_idx*TSTEPS + t)*HIDDEN + w*16 + jl] = hb;
    }
}

// ---------------------------------------------------------------- K3:
// Fused vocab GEMM + per-row softmax partials. BM=64, BN=256, 256 thr (4 waves).
// Grid (bm fastest): consecutive blocks share the same WvT slice -> XCD-L2 reuse.
__global__ __launch_bounds__(256) void vocab_gemm(const unsigned short* __restrict__ hs,
        const unsigned short* __restrict__ WvT, const float* __restrict__ bvoc,
        const int* __restrict__ captions, float* __restrict__ pmax,
        float* __restrict__ psum, float* __restrict__ tlog){
    int bm = blockIdx.x;    // 0..63  (fastest -> siblings share bn's WvT slice)
    int bn = blockIdx.y;    // 0..124
    int tid = threadIdx.x;
    int wv = tid >> 6, L = tid & 63;
    int q = L >> 4, ln = L & 15;
    __shared__ int   tgt_s[64];
    __shared__ float wmax_s[4][64], wsum_s[4][64];
    if (tid < 64){
        int rg = bm*64 + tid;
        tgt_s[tid] = captions[(rg >> 8)*257 + (rg & 255) + 1];
    }
    __syncthreads();
    f32x4 acc[4][4];
    for (int mt=0;mt<4;++mt) for (int nt=0;nt<4;++nt) acc[mt][nt] = (f32x4){0.f,0.f,0.f,0.f};
    int colb = bn*256 + wv*64;
    for (int kt = 0; kt < 16; ++kt){
        short8 a[4], bb[4];
        #pragma unroll
        for (int mt=0;mt<4;++mt){
            int row = bm*64 + mt*16 + ln;
            a[mt] = *(const short8*)(hs + (long)row*HIDDEN + kt*32 + q*8);
        }
        #pragma unroll
        for (int nt=0;nt<4;++nt){
            int v = colb + nt*16 + ln;
            bb[nt] = *(const short8*)(WvT + (long)v*HIDDEN + kt*32 + q*8);
        }
        #pragma unroll
        for (int mt=0;mt<4;++mt)
            #pragma unroll
            for (int nt=0;nt<4;++nt)
                acc[mt][nt] = __builtin_amdgcn_mfma_f32_16x16x32_bf16(a[mt], bb[nt], acc[mt][nt], 0,0,0);
    }
    float bv[4];
    #pragma unroll
    for (int nt=0;nt<4;++nt) bv[nt] = bvoc[colb + nt*16 + ln];
    #pragma unroll
    for (int mt=0;mt<4;++mt) for (int nt=0;nt<4;++nt) for (int r=0;r<4;++r)
        acc[mt][nt][r] += bv[nt];
    // target-logit grab (exactly one lane grid-wide matches per row)
    #pragma unroll
    for (int mt=0;mt<4;++mt) for (int r=0;r<4;++r){
        int rl = mt*16 + q*4 + r;
        int tg = tgt_s[rl] - colb;
        if (tg >= 0 && tg < 64){
            int nt = tg >> 4;
            if ((tg & 15) == ln) tlog[bm*64 + rl] = acc[mt][nt][r];
        }
    }
    // per-row max & sumexp over this block's 256 cols
    #pragma unroll
    for (int mt=0;mt<4;++mt){
        #pragma unroll
        for (int r=0;r<4;++r){
            float m = fmaxf(fmaxf(acc[mt][0][r],acc[mt][1][r]), fmaxf(acc[mt][2][r],acc[mt][3][r]));
            for (int d=1; d<16; d<<=1) m = fmaxf(m, __shfl_xor(m, d, 16));
            float s = __expf(acc[mt][0][r]-m) + __expf(acc[mt][1][r]-m)
                    + __expf(acc[mt][2][r]-m) + __expf(acc[mt][3][r]-m);
            for (int d=1; d<16; d<<=1) s += __shfl_xor(s, d, 16);
            if (ln == 0){ int rl = mt*16 + q*4 + r; wmax_s[wv][rl] = m; wsum_s[wv][rl] = s; }
        }
    }
    __syncthreads();
    if (tid < 64){
        float M = fmaxf(fmaxf(wmax_s[0][tid],wmax_s[1][tid]), fmaxf(wmax_s[2][tid],wmax_s[3][tid]));
        float S = 0.f;
        for (int ww=0; ww<4; ++ww) S += wsum_s[ww][tid]*__expf(wmax_s[ww][tid]-M);
        pmax[(long)bn*NROWS + bm*64 + tid] = M;
        psum[(long)bn*NROWS + bm*64 + tid] = S;
    }
}

// ---------------------------------------------------------------- K4:
// combine 125 partials per row -> lse -> masked NLL -> loss/N
__global__ __launch_bounds__(256) void reduce_loss(const float* __restrict__ pmax,
        const float* __restrict__ psum, const float* __restrict__ tlog,
        const int* __restrict__ captions, float* __restrict__ out){
    int r = blockIdx.x*256 + threadIdx.x;
    float M = -1e30f;
    for (int p=0;p<NVB;++p) M = fmaxf(M, pmax[(long)p*NROWS + r]);
    float S = 0.f;
    for (int p=0;p<NVB;++p) S += psum[(long)p*NROWS + r]*__expf(pmax[(long)p*NROWS + r]-M);
    float lse = M + logf(S);
    float nll = lse - tlog[r];
    int tok = captions[(r >> 8)*257 + (r & 255) + 1];
    float val = (tok != 0) ? nll : 0.f;
    __shared__ float red[256];
    red[threadIdx.x] = val; __syncthreads();
    for (int s=128; s>0; s>>=1){
        if (threadIdx.x < s) red[threadIdx.x] += red[threadIdx.x+s];
        __syncthreads();
    }
    if (threadIdx.x == 0) atomicAdd(out, red[0] * (1.0f/16.0f));
}

// ---------------------------------------------------------------- launch
extern "C" void kernel_launch(void* const* d_in, const int* in_sizes, int n_in,
                              void* d_out, int out_size, void* d_ws, size_t ws_size,
                              hipStream_t stream){
    const int*   captions = (const int*)  d_in[0];
    const float* Wemb     = (const float*)d_in[1];
    const float* Wx       = (const float*)d_in[2];
    const float* Wh       = (const float*)d_in[3];
    const float* b        = (const float*)d_in[4];
    const float* Wv       = (const float*)d_in[5];
    const float* bvoc     = (const float*)d_in[6];
    const float* h_init   = (const float*)d_in[7];

    char* ws = (char*)d_ws;
    float*          xw   = (float*)         (ws + 0);          // 33554432 B
    unsigned short* WvT  = (unsigned short*)(ws + 33554432);   // 32768000 B
    unsigned short* hs   = (unsigned short*)(ws + 66322432);   //  4194304 B
    float*          pmax = (float*)         (ws + 70516736);   //  2048000 B
    float*          psum = (float*)         (ws + 72564736);   //  2048000 B
    float*          tlog = (float*)         (ws + 74612736);   //    16384 B
    unsigned short* Whp  = (unsigned short*)(ws + 74629120);   //  2097152 B
    u64*            hx   = (u64*)           (ws + 76726272);   //    65536 B (2 bufs x 4096 u64)

    float* out_f = (float*)d_out;

    (void)hipMemsetAsync(d_out, 0, sizeof(float), stream);

    hipLaunchKernelGGL(wv_transpose, dim3(500, 8), dim3(256), 0, stream, Wv, WvT);
    hipLaunchKernelGGL(whp_prep,     dim3(NWG),    dim3(256), 0, stream, Wh, Whp);
    hipLaunchKernelGGL(hg_init,      dim3(16),     dim3(256), 0, stream, h_init, hx);
    hipLaunchKernelGGL(embed_xw,     dim3(512),    dim3(256), 0, stream, captions, Wemb, Wx, b, xw);
    hipLaunchKernelGGL(lstm_mfma,    dim3(NWG),    dim3(256), 0, stream, xw, Whp, hx, hs);
    hipLaunchKernelGGL(vocab_gemm,   dim3(64,NVB), dim3(256), 0, stream, hs, WvT, bvoc, captions, pmax, psum, tlog);
    hipLaunchKernelGGL(reduce_loss,  dim3(16),     dim3(256), 0, stream, pmax, psum, tlog, captions, out_f);
}

// Round 8
// 1158.969 us; speedup vs baseline: 2.6251x; 1.2204x over previous
//
#include <hip/hip_runtime.h>

#define VOCAB   32000
#define WORDVEC 256
#define HIDDEN  512
#define TSTEPS  256
#define NBATCH  16
#define NROWS   (TSTEPS*NBATCH)   // 4096
#define GATES   (4*HIDDEN)        // 2048
#define NVB     125               // 32000/256
#define NWG     32                // LSTM workgroups (32 x 16 hidden units)

typedef __attribute__((ext_vector_type(8))) short short8;
typedef __attribute__((ext_vector_type(4))) float f32x4;
typedef unsigned long long u64;

__device__ __forceinline__ unsigned short f2bf(float x){
    union { float f; unsigned int u; } v; v.f = x;
    unsigned int r = v.u + 0x7fffu + ((v.u >> 16) & 1u);
    return (unsigned short)(r >> 16);
}

// ---------------------------------------------------------------- K0a:
// W_vocab (fp32 [512][32000]) -> WvP: MFMA-B-fragment-linear bf16.
// Fragment (vb, kt) = 64 lanes x 8 shorts contiguous (1KB):
//   lane L=(q,ln), short j  <->  element (v = vb*16+ln, k = kt*32+q*8+j)
__global__ __launch_bounds__(256) void wv_pack(const float* __restrict__ Wv, unsigned short* __restrict__ WvP){
    __shared__ float s[64][65];
    int v0 = blockIdx.x * 64;     // 500 blocks
    int k0 = blockIdx.y * 64;     // 8 blocks
    int tid = threadIdx.x;
    for (int i = 0; i < 16; ++i){
        int lin = tid + i*256;
        int kk = lin >> 6, vv = lin & 63;
        s[kk][vv] = Wv[(long)(k0+kk)*VOCAB + v0 + vv];
    }
    __syncthreads();
    for (int i = 0; i < 2; ++i){
        int lr = tid + i*256;          // 0..511 lane-rows
        int f  = lr >> 6;              // 0..7: vbl(0..3) x ktl(0..1)
        int vbl = f >> 1, ktl = f & 1;
        int L = lr & 63, q = L >> 4, ln = L & 15;
        short8 o;
        #pragma unroll
        for (int j = 0; j < 8; ++j)
            o[j] = (short)f2bf(s[ktl*32 + q*8 + j][vbl*16 + ln]);
        long vb = blockIdx.x*4 + vbl;
        long kt = blockIdx.y*2 + ktl;
        *(short8*)(WvP + ((vb*16 + kt)*64 + L)*8) = o;
    }
}

// ---------------------------------------------------------------- K0b:
// Wh (fp32 [512][2048]) -> Whp: per-WG MFMA-B-fragment-ordered bf16 image.
__global__ void whp_prep(const float* __restrict__ Wh, unsigned short* __restrict__ Whp){
    int w = blockIdx.x; int tid = threadIdx.x;   // 32 blocks x 256 thr
    for (int item = tid; item < 4096; item += 256){
        int f = item >> 6;          // 0..63
        int L = item & 63;
        int kt = f >> 2, nt = f & 3;
        int q = L >> 4, ln = L & 15;
        int col = nt*HIDDEN + w*16 + ln;   // gate nt, unit w*16+ln
        short8 vvec;
        for (int jj = 0; jj < 8; ++jj){
            int k = kt*32 + q*8 + jj;
            vvec[jj] = (short)f2bf(Wh[(long)k*GATES + col]);
        }
        *(short8*)(Whp + ((long)w*4096 + item)*8) = vvec;
    }
}

// ---------------------------------------------------------------- K0c:
// h_0 into exchange buffer 0 as tagged pairs: u64 = {tag=0 | bf16 hi | bf16 lo}.
__global__ void hg_init(const float* __restrict__ h_init, u64* __restrict__ hx){
    int p = blockIdx.x*256 + threadIdx.x;   // 4096 pairs
    int fq = p >> 6;
    int j  = (p & 3) * 2;
    int u0 = (fq>>2)*32 + (fq&3)*8 + j;
    u64 pk = (u64)f2bf(h_init[u0]) | ((u64)f2bf(h_init[u0+1]) << 16);   // tag 0
    hx[p] = pk;
}

// ---------------------------------------------------------------- K1:
// xw[r=t*16+n][k] = b[k] + sum_d W_embed[cap_in[n][t]][d] * Wx[d][k]   (fp32)
__global__ __launch_bounds__(256) void embed_xw(const int* __restrict__ captions,
        const float* __restrict__ Wemb, const float* __restrict__ Wx,
        const float* __restrict__ b, float* __restrict__ xw){
    __shared__ float xs[8][WORDVEC];
    __shared__ int toks[8];
    int tid = threadIdx.x;
    int r0 = blockIdx.x * 8;
    if (tid < 8){
        int r = r0 + tid; int t = r >> 4, n = r & 15;
        toks[tid] = captions[n*257 + t];
    }
    __syncthreads();
    for (int i = 0; i < 8; ++i){
        int lin = tid + i*256;
        int ri = lin >> 8, d = lin & 255;
        xs[ri][d] = Wemb[(long)toks[ri]*WORDVEC + d];
    }
    __syncthreads();
    float4 b0 = *(const float4*)(b + tid*4);
    float4 b1 = *(const float4*)(b + 1024 + tid*4);
    float acc[8][8];
    for (int ri = 0; ri < 8; ++ri){
        acc[ri][0]=b0.x; acc[ri][1]=b0.y; acc[ri][2]=b0.z; acc[ri][3]=b0.w;
        acc[ri][4]=b1.x; acc[ri][5]=b1.y; acc[ri][6]=b1.z; acc[ri][7]=b1.w;
    }
    for (int d = 0; d < WORDVEC; ++d){
        float4 w0 = *(const float4*)(Wx + (long)d*GATES + tid*4);
        float4 w1 = *(const float4*)(Wx + (long)d*GATES + 1024 + tid*4);
        #pragma unroll
        for (int ri = 0; ri < 8; ++ri){
            float xv = xs[ri][d];
            acc[ri][0] += xv*w0.x; acc[ri][1] += xv*w0.y;
            acc[ri][2] += xv*w0.z; acc[ri][3] += xv*w0.w;
            acc[ri][4] += xv*w1.x; acc[ri][5] += xv*w1.y;
            acc[ri][6] += xv*w1.z; acc[ri][7] += xv*w1.w;
        }
    }
    for (int ri = 0; ri < 8; ++ri){
        float4 o0 = {acc[ri][0],acc[ri][1],acc[ri][2],acc[ri][3]};
        float4 o1 = {acc[ri][4],acc[ri][5],acc[ri][6],acc[ri][7]};
        *(float4*)(xw + (long)(r0+ri)*GATES + tid*4) = o0;
        *(float4*)(xw + (long)(r0+ri)*GATES + 1024 + tid*4) = o1;
    }
}

// ---------------------------------------------------------------- K2:
// Batched LSTM, fence-free + flag-free, tagged-u64 h exchange (round 7).
// Round 8: spin poll (no s_sleep), __expf-only gates, hsP written in
// A-fragment-linear layout for the vocab GEMM.
__global__ __launch_bounds__(256) void lstm_mfma(const float* __restrict__ xw,
        const unsigned short* __restrict__ Whp, u64* __restrict__ hx,
        unsigned short* __restrict__ hsP){
    __shared__ unsigned int hstage[4096];   // 16 KB: h_t as bf16 pairs (tags stripped)
    __shared__ float a_s[4][16][16];        // 4 KB
    int w = blockIdx.x;          // 0..31
    int tid = threadIdx.x;       // 0..255
    int wv = tid >> 6;           // wave = gate = N-tile (0..3)
    int L = tid & 63;
    int q = L >> 4, ln = L & 15;
    int s_idx = tid >> 4, jl = tid & 15;   // (sequence, local hidden unit)

    // Wh B-fragments -> registers (wave wv uses fragments kt*4+wv only)
    short8 bw[16];
    #pragma unroll
    for (int kt = 0; kt < 16; ++kt)
        bw[kt] = *(const short8*)(Whp + ((long)w*4096 + (kt*4+wv)*64 + L)*8);

    float c_r = 0.f;
    // publish pair index: fq for this WG's (jl) + seq + pair-within-8
    int fq_pub = (w>>1)*4 + (w&1)*2 + (jl>>3);
    int pubIdx = fq_pub*64 + s_idx*4 + ((jl>>1)&3);
    // hsP store address pieces (row = s_idx*256 + t; unit u = w*16+jl)
    int kt_h = w >> 1;
    int q_h  = ((w & 1) << 1) | (jl >> 3);
    int j_h  = jl & 7;

    for (int t = 0; t < TSTEPS; ++t){
        // xw loads first: HBM latency overlaps the poll
        long xb = (long)(t*16 + s_idx)*GATES + w*16 + jl;
        float xg0 = xw[xb], xg1 = xw[xb+512], xg2 = xw[xb+1024], xg3 = xw[xb+1536];

        const u64* hr = hx + (t & 1)*4096;
        u64*       hw = hx + ((t+1) & 1)*4096;

        // ---- poll + stage: 16 coalesced u64/thread, spin until all tags == t
        u64 v[16];
        #pragma unroll
        for (int i = 0; i < 16; ++i)
            v[i] = __hip_atomic_load(hr + tid + i*256, __ATOMIC_RELAXED, __HIP_MEMORY_SCOPE_AGENT);
        for (;;){
            u64 bad = 0;
            #pragma unroll
            for (int i = 0; i < 16; ++i) bad |= (v[i] >> 32) ^ (u64)(unsigned)t;
            if (!bad) break;
            #pragma unroll
            for (int i = 0; i < 16; ++i)
                v[i] = __hip_atomic_load(hr + tid + i*256, __ATOMIC_RELAXED, __HIP_MEMORY_SCOPE_AGENT);
        }
        #pragma unroll
        for (int i = 0; i < 16; ++i) hstage[tid + i*256] = (unsigned)v[i];
        __syncthreads();   // S1: stage complete (also orders vs prev a_s reads)

        // ---- MFMA: A-frag (kt,q,ln) = 4 contiguous u32 (linear sweep)
        f32x4 acc = {0.f,0.f,0.f,0.f};
        #pragma unroll
        for (int kt = 0; kt < 16; ++kt){
            short8 a = *(const short8*)((const unsigned short*)hstage + (kt*256 + q*64 + ln*4)*2);
            acc = __builtin_amdgcn_mfma_f32_16x16x32_bf16(a, bw[kt], acc, 0, 0, 0);
        }
        // D layout: row(seq) = q*4+reg, col(unit) = ln; wave wv = gate
        #pragma unroll
        for (int r = 0; r < 4; ++r) a_s[wv][q*4 + r][ln] = acc[r];
        __syncthreads();   // S2: a_s complete (also: all hstage reads done)

        // ---- gate phase: thread -> (s_idx, jl); __expf-only nonlinearities
        float ai = a_s[0][s_idx][jl] + xg0;
        float af = a_s[1][s_idx][jl] + xg1;
        float ao = a_s[2][s_idx][jl] + xg2;
        float ag = a_s[3][s_idx][jl] + xg3;
        float ig = 1.f/(1.f + __expf(-ai));
        float fg = 1.f/(1.f + __expf(-af));
        float og = 1.f/(1.f + __expf(-ao));
        float gg = 2.f/(1.f + __expf(-2.f*ag)) - 1.f;
        c_r = fg*c_r + ig*gg;
        float hv = og * (2.f/(1.f + __expf(-2.f*c_r)) - 1.f);
        unsigned short hb = f2bf(hv);

        // ---- publish: pack {tag=t+1 | h[jl+1] | h[jl]}, fire-and-forget
        int hv32 = (int)hb;
        int other = __shfl(hv32, L ^ 1);
        if ((jl & 1) == 0){
            u64 pk = (u64)(unsigned short)hv32
                   | ((u64)(unsigned short)other << 16)
                   | ((u64)(unsigned)(t+1) << 32);
            __hip_atomic_store(hw + pubIdx, pk, __ATOMIC_RELAXED, __HIP_MEMORY_SCOPE_AGENT);
        }
        // hsP history store, A-fragment-linear (off critical path, plain cached)
        int rb = s_idx*16 + (t >> 4);
        hsP[(((long)(rb*16 + kt_h))*64 + q_h*16 + (t & 15))*8 + j_h] = hb;
    }
}

// ---------------------------------------------------------------- K3:
// Fused vocab GEMM + per-row softmax partials. BM=64, BN=256, 256 thr (4 waves).
// A (hsP) and B (WvP) both fragment-linear: every load = dense 1KB wave-load.
__global__ __launch_bounds__(256) void vocab_gemm(const unsigned short* __restrict__ hsP,
        const unsigned short* __restrict__ WvP, const float* __restrict__ bvoc,
        const int* __restrict__ captions, float* __restrict__ pmax,
        float* __restrict__ psum, float* __restrict__ tlog){
    int bm = blockIdx.x;    // 0..63  (fastest -> siblings share bn's WvP slice)
    int bn = blockIdx.y;    // 0..124
    int tid = threadIdx.x;
    int wv = tid >> 6, L = tid & 63;
    int q = L >> 4, ln = L & 15;
    __shared__ int   tgt_s[64];
    __shared__ float wmax_s[4][64], wsum_s[4][64];
    if (tid < 64){
        int rg = bm*64 + tid;
        tgt_s[tid] = captions[(rg >> 8)*257 + (rg & 255) + 1];
    }
    __syncthreads();
    f32x4 acc[4][4];
    for (int mt=0;mt<4;++mt) for (int nt=0;nt<4;++nt) acc[mt][nt] = (f32x4){0.f,0.f,0.f,0.f};
    int colb = bn*256 + wv*64;
    const unsigned short* aB = hsP + ((long)(bm*4)*16)*512;        // rb = bm*4 + mt
    const unsigned short* bB = WvP + ((long)(bn*16 + wv*4)*16)*512; // vb = bn*16+wv*4+nt
    #pragma unroll 4
    for (int kt = 0; kt < 16; ++kt){
        short8 a[4], bb[4];
        #pragma unroll
        for (int mt=0;mt<4;++mt)
            a[mt] = *(const short8*)(aB + ((long)(mt*16 + kt)*64 + L)*8);
        #pragma unroll
        for (int nt=0;nt<4;++nt)
            bb[nt] = *(const short8*)(bB + ((long)(nt*16 + kt)*64 + L)*8);
        #pragma unroll
        for (int mt=0;mt<4;++mt)
            #pragma unroll
            for (int nt=0;nt<4;++nt)
                acc[mt][nt] = __builtin_amdgcn_mfma_f32_16x16x32_bf16(a[mt], bb[nt], acc[mt][nt], 0,0,0);
    }
    float bv[4];
    #pragma unroll
    for (int nt=0;nt<4;++nt) bv[nt] = bvoc[colb + nt*16 + ln];
    #pragma unroll
    for (int mt=0;mt<4;++mt) for (int nt=0;nt<4;++nt) for (int r=0;r<4;++r)
        acc[mt][nt][r] += bv[nt];
    // target-logit grab (exactly one lane grid-wide matches per row)
    #pragma unroll
    for (int mt=0;mt<4;++mt) for (int r=0;r<4;++r){
        int rl = mt*16 + q*4 + r;
        int tg = tgt_s[rl] - colb;
        if (tg >= 0 && tg < 64){
            int nt = tg >> 4;
            if ((tg & 15) == ln) tlog[bm*64 + rl] = acc[mt][nt][r];
        }
    }
    // per-row max & sumexp over this block's 256 cols
    #pragma unroll
    for (int mt=0;mt<4;++mt){
        #pragma unroll
        for (int r=0;r<4;++r){
            float m = fmaxf(fmaxf(acc[mt][0][r],acc[mt][1][r]), fmaxf(acc[mt][2][r],acc[mt][3][r]));
            for (int d=1; d<16; d<<=1) m = fmaxf(m, __shfl_xor(m, d, 16));
            float s = __expf(acc[mt][0][r]-m) + __expf(acc[mt][1][r]-m)
                    + __expf(acc[mt][2][r]-m) + __expf(acc[mt][3][r]-m);
            for (int d=1; d<16; d<<=1) s += __shfl_xor(s, d, 16);
            if (ln == 0){ int rl = mt*16 + q*4 + r; wmax_s[wv][rl] = m; wsum_s[wv][rl] = s; }
        }
    }
    __syncthreads();
    if (tid < 64){
        float M = fmaxf(fmaxf(wmax_s[0][tid],wmax_s[1][tid]), fmaxf(wmax_s[2][tid],wmax_s[3][tid]));
        float S = 0.f;
        for (int ww=0; ww<4; ++ww) S += wsum_s[ww][tid]*__expf(wmax_s[ww][tid]-M);
        pmax[(long)bn*NROWS + bm*64 + tid] = M;
        psum[(long)bn*NROWS + bm*64 + tid] = S;
    }
}

// ---------------------------------------------------------------- K4:
// combine 125 partials per row -> lse -> masked NLL -> loss/N
__global__ __launch_bounds__(256) void reduce_loss(const float* __restrict__ pmax,
        const float* __restrict__ psum, const float* __restrict__ tlog,
        const int* __restrict__ captions, float* __restrict__ out){
    int r = blockIdx.x*256 + threadIdx.x;
    float M = -1e30f;
    for (int p=0;p<NVB;++p) M = fmaxf(M, pmax[(long)p*NROWS + r]);
    float S = 0.f;
    for (int p=0;p<NVB;++p) S += psum[(long)p*NROWS + r]*__expf(pmax[(long)p*NROWS + r]-M);
    float lse = M + logf(S);
    float nll = lse - tlog[r];
    int tok = captions[(r >> 8)*257 + (r & 255) + 1];
    float val = (tok != 0) ? nll : 0.f;
    __shared__ float red[256];
    red[threadIdx.x] = val; __syncthreads();
    for (int s=128; s>0; s>>=1){
        if (threadIdx.x < s) red[threadIdx.x] += red[threadIdx.x+s];
        __syncthreads();
    }
    if (threadIdx.x == 0) atomicAdd(out, red[0] * (1.0f/16.0f));
}

// ---------------------------------------------------------------- launch
extern "C" void kernel_launch(void* const* d_in, const int* in_sizes, int n_in,
                              void* d_out, int out_size, void* d_ws, size_t ws_size,
                              hipStream_t stream){
    const int*   captions = (const int*)  d_in[0];
    const float* Wemb     = (const float*)d_in[1];
    const float* Wx       = (const float*)d_in[2];
    const float* Wh       = (const float*)d_in[3];
    const float* b        = (const float*)d_in[4];
    const float* Wv       = (const float*)d_in[5];
    const float* bvoc     = (const float*)d_in[6];
    const float* h_init   = (const float*)d_in[7];

    char* ws = (char*)d_ws;
    float*          xw   = (float*)         (ws + 0);          // 33554432 B
    unsigned short* WvP  = (unsigned short*)(ws + 33554432);   // 32768000 B
    unsigned short* hsP  = (unsigned short*)(ws + 66322432);   //  4194304 B
    float*          pmax = (float*)         (ws + 70516736);   //  2048000 B
    float*          psum = (float*)         (ws + 72564736);   //  2048000 B
    float*          tlog = (float*)         (ws + 74612736);   //    16384 B
    unsigned short* Whp  = (unsigned short*)(ws + 74629120);   //  2097152 B
    u64*            hx   = (u64*)           (ws + 76726272);   //    65536 B (2 bufs x 4096 u64)

    float* out_f = (float*)d_out;

    (void)hipMemsetAsync(d_out, 0, sizeof(float), stream);

    hipLaunchKernelGGL(wv_pack,      dim3(500, 8), dim3(256), 0, stream, Wv, WvP);
    hipLaunchKernelGGL(whp_prep,     dim3(NWG),    dim3(256), 0, stream, Wh, Whp);
    hipLaunchKernelGGL(hg_init,      dim3(16),     dim3(256), 0, stream, h_init, hx);
    hipLaunchKernelGGL(embed_xw,     dim3(512),    dim3(256), 0, stream, captions, Wemb, Wx, b, xw);
    hipLaunchKernelGGL(lstm_mfma,    dim3(NWG),    dim3(256), 0, stream, xw, Whp, hx, hsP);
    hipLaunchKernelGGL(vocab_gemm,   dim3(64,NVB), dim3(256), 0, stream, hsP, WvP, bvoc, captions, pmax, psum, tlog);
    hipLaunchKernelGGL(reduce_loss,  dim3(16),     dim3(256), 0, stream, pmax, psum, tlog, captions, out_f);
}